// Round 12
// baseline (253.087 us; speedup 1.0000x reference)
//
#include <hip/hip_runtime.h>
#include <hip/hip_bf16.h>
#include <math.h>

#define BATCH   2
#define SEQ     2048
#define D_IN    2048
#define NHEAD   16
#define QK_ROPE 64
#define QK_NOPE 64
#define QK_HEAD 128
#define V_HEAD  128
#define KV_RANK 512
#define KV_W    640          // kv row stride (576 padded to 640)
#define NTOK    (BATCH*SEQ)  // 4096
#define EPS_F   1e-6f

typedef unsigned short u16;
typedef short bf16x8 __attribute__((ext_vector_type(8)));
typedef float f32x4  __attribute__((ext_vector_type(4)));

__device__ __forceinline__ u16 f2bf(float f) {
    unsigned u = __float_as_uint(f);
    return (u16)((u + 0x7fffu + ((u >> 16) & 1u)) >> 16);
}
__device__ __forceinline__ float bf2f(u16 u) {
    return __uint_as_float(((unsigned)u) << 16);
}
__device__ __forceinline__ float exp2_hw(float x) {
    float r;
    asm volatile("v_exp_f32 %0, %1\n\ts_nop 0" : "=v"(r) : "v"(x));
    return r;
}
__device__ __forceinline__ void gload16(const void* g, void* l) {
    __builtin_amdgcn_global_load_lds((const __attribute__((address_space(1))) unsigned int*)g,
                                     (__attribute__((address_space(3))) unsigned int*)l, 16, 0, 0);
}

// ---------------- fused preamble: convert + 4 transposes + rope table -------
__device__ __forceinline__ void transpose_sec(const float* __restrict__ src,
                                              u16* __restrict__ dst,
                                              int N, int K, int bx, int by,
                                              float (*tile)[33], int tid) {
    const int tx = tid & 31, ty = tid >> 5;
    const int nb = bx * 32, kb = by * 32;
#pragma unroll
    for (int i = 0; i < 4; ++i) {
        int k = kb + ty + 8 * i, n = nb + tx;
        tile[ty + 8 * i][tx] = (n < N) ? src[(size_t)k * N + n] : 0.f;
    }
    __syncthreads();
#pragma unroll
    for (int i = 0; i < 4; ++i) {
        int n = nb + ty + 8 * i, k = kb + tx;
        dst[(size_t)n * K + k] = f2bf(tile[tx][ty + 8 * i]);
    }
}

__global__ __launch_bounds__(256) void prep(const float* __restrict__ x, u16* __restrict__ x_bf,
                                            const float* __restrict__ wq, u16* __restrict__ wqT,
                                            const float* __restrict__ wkva, u16* __restrict__ wkvaT,
                                            const float* __restrict__ wkvb, u16* __restrict__ wkvbT,
                                            const float* __restrict__ op, u16* __restrict__ opT,
                                            float* __restrict__ tab) {
    __shared__ float tile[32][33];
    const int idx = blockIdx.x;
    const int tid = threadIdx.x;
    if (idx < 8192) {                      // x fp32 -> bf16, 4/thread
        int gid = idx * 256 + tid;
        float4 v = ((const float4*)x)[gid];
        unsigned lo = (unsigned)f2bf(v.x) | ((unsigned)f2bf(v.y) << 16);
        unsigned hi = (unsigned)f2bf(v.z) | ((unsigned)f2bf(v.w) << 16);
        ((uint2*)x_bf)[gid] = make_uint2(lo, hi);
    } else if (idx < 12288) {              // w_query^T
        int s = idx - 8192;
        transpose_sec(wq, wqT, 2048, 2048, s % 64, s / 64, tile, tid);
    } else if (idx < 13568) {              // wkv_a^T (576 -> pad 640)
        int s = idx - 12288;
        transpose_sec(wkva, wkvaT, 576, 2048, s % 20, s / 20, tile, tid);
    } else if (idx < 15104) {              // wkv_b^T
        int s = idx - 13568;
        transpose_sec(wkvb, wkvbT, 3072, 512, s % 96, s / 96, tile, tid);
    } else if (idx < 19200) {              // out_proj^T
        int s = idx - 15104;
        transpose_sec(op, opT, 2048, 2048, s % 64, s / 64, tile, tid);
    } else {                               // rope cos/sin table
        int gid = (idx - 19200) * 256 + tid;  // < SEQ*32
        int i = gid & 31, s = gid >> 5;
        float freq = __expf(-(float)(2 * i) / 64.0f * 9.210340371976184f);
        float ang = (float)s * freq;
        tab[2 * gid]     = cosf(ang);
        tab[2 * gid + 1] = sinf(ang);
    }
}

// ============ 256x256 bf16 GEMM, BK=32, 3-buf 2-tile-deep pipeline ==========
// Swizzle for 64B rows: slot ^= ((row&3)^((row>>2)&3)) -> rows {r,r+4,r+8,r+12}
// land on distinct 16B slots (2-way bank access = free). Both sides: inverse-
// swizzled global source on stage, swizzled ds_read.
template <int EPI>
__global__ __launch_bounds__(512, 1) void gemm256(const u16* __restrict__ A,
                                                  const u16* __restrict__ BT,
                                                  void* __restrict__ out0,
                                                  void* __restrict__ out1,
                                                  const float* __restrict__ tab,
                                                  int gx, int N, int K, float oscale) {
    __shared__ u16 lds[49152];  // 96KB
    const int tid = threadIdx.x;
    const int w = tid >> 6, l = tid & 63;
    const int lr = l & 15, lg = l >> 4;
    const int wr = w >> 2;          // 0..1  (M half)
    const int wc = w & 3;           // 0..3  (N quarter)
    const int nwg = gridDim.x, q8 = nwg >> 3;
    const int wg = (blockIdx.x & 7) * q8 + (blockIdx.x >> 3);
    const int row0 = (wg / gx) * 256, col0 = (wg % gx) * 256;
    const int NT = K >> 5;

    f32x4 acc[8][4];
#pragma unroll
    for (int m = 0; m < 8; ++m)
#pragma unroll
        for (int n = 0; n < 4; ++n) acc[m][n] = (f32x4){0.f, 0.f, 0.f, 0.f};

    // stage full A k-tile (256 rows x 32 cols = 16KB, 2 gloads/thread)
    auto stageA = [&](int bufi, int kt) {
        u16* base = lds + bufi * 8192;
        const u16* g = A + (size_t)row0 * K + kt * 32;
#pragma unroll
        for (int i = 0; i < 2; ++i) {
            int L = (i * 512 + tid) * 16;                 // linear LDS byte
            int f = ((L >> 6) ^ (L >> 8)) & 3;
            int s = L ^ (f << 4);                         // inverse-swizzled src
            gload16(g + (size_t)(L >> 6) * K + ((s & 63) >> 1), base + (L >> 1));
        }
    };
    auto stageB = [&](int bufi, int kt) {
        u16* base = lds + 24576 + bufi * 8192;
        const u16* g = BT + (size_t)col0 * K + kt * 32;
#pragma unroll
        for (int i = 0; i < 2; ++i) {
            int L = (i * 512 + tid) * 16;
            int f = ((L >> 6) ^ (L >> 8)) & 3;
            int s = L ^ (f << 4);
            gload16(g + (size_t)(L >> 6) * K + ((s & 63) >> 1), base + (L >> 1));
        }
    };

    // prologue: tiles 0 and 1 (4 loads each, oldest-first)
    stageA(0, 0); stageB(0, 0); stageA(1, 1); stageB(1, 1);

    for (int t = 0; t < NT; ++t) {
        const int buf = t % 3, nb2 = (t + 2) % 3;
        u16* Ab = lds + buf * 8192;
        u16* Bb = lds + 24576 + buf * 8192;
        if (t + 1 < NT) asm volatile("s_waitcnt vmcnt(4)" ::: "memory");
        else            asm volatile("s_waitcnt vmcnt(0)" ::: "memory");
        __builtin_amdgcn_s_barrier();
        __builtin_amdgcn_sched_barrier(0);

        bf16x8 bfg[4], af[4];
        // ---- phase 0: B frags + A frags m0-3, stage A(t+2) ----
#pragma unroll
        for (int n = 0; n < 4; ++n) {
            int row = wc * 64 + n * 16 + lr;
            int fr = (row ^ (row >> 2)) & 3;
            bfg[n] = *(const bf16x8*)&Bb[(row * 64 + ((lg ^ fr) << 4)) >> 1];
        }
#pragma unroll
        for (int i = 0; i < 4; ++i) {
            int row = wr * 128 + i * 16 + lr;
            int fr = (row ^ (row >> 2)) & 3;
            af[i] = *(const bf16x8*)&Ab[(row * 64 + ((lg ^ fr) << 4)) >> 1];
        }
        if (t + 2 < NT) stageA(nb2, t + 2);
        __builtin_amdgcn_s_barrier();
        asm volatile("s_waitcnt lgkmcnt(0)" ::: "memory");
        __builtin_amdgcn_sched_barrier(0);
        __builtin_amdgcn_s_setprio(1);
#pragma unroll
        for (int i = 0; i < 4; ++i)
#pragma unroll
            for (int n = 0; n < 4; ++n)
                acc[i][n] = __builtin_amdgcn_mfma_f32_16x16x32_bf16(af[i], bfg[n], acc[i][n], 0, 0, 0);
        __builtin_amdgcn_s_setprio(0);

        // ---- phase 1: A frags m4-7, stage B(t+2) ----
#pragma unroll
        for (int i = 0; i < 4; ++i) {
            int row = wr * 128 + (4 + i) * 16 + lr;
            int fr = (row ^ (row >> 2)) & 3;
            af[i] = *(const bf16x8*)&Ab[(row * 64 + ((lg ^ fr) << 4)) >> 1];
        }
        if (t + 2 < NT) stageB(nb2, t + 2);
        __builtin_amdgcn_s_barrier();
        asm volatile("s_waitcnt lgkmcnt(0)" ::: "memory");
        __builtin_amdgcn_sched_barrier(0);
        __builtin_amdgcn_s_setprio(1);
#pragma unroll
        for (int i = 0; i < 4; ++i)
#pragma unroll
            for (int n = 0; n < 4; ++n)
                acc[4 + i][n] = __builtin_amdgcn_mfma_f32_16x16x32_bf16(af[i], bfg[n], acc[4 + i][n], 0, 0, 0);
        __builtin_amdgcn_s_setprio(0);
    }

    // ---- epilogues: row = row0+wr*128+m*16+4lg+j, col = col0+wc*64+n*16+lr --
    if (EPI == 0) {
        u16* qp = (u16*)out0;
        float* kvp = (float*)out1;
        const bool pe = (wc & 1);  // within-head offset >= 64 -> rope half
#pragma unroll
        for (int m = 0; m < 8; ++m)
#pragma unroll
            for (int n = 0; n < 4; ++n) {
                int c = col0 + wc * 64 + n * 16 + lr;
#pragma unroll
                for (int j = 0; j < 4; ++j) {
                    int r = row0 + wr * 128 + m * 16 + 4 * lg + j;
                    float v = acc[m][n][j];
                    if (c < 2048) {
                        v *= oscale;
                        if (pe) {
                            int s = r & (SEQ - 1);
                            int ip = (16 * n + lr) >> 1;
                            float2 cs = ((const float2*)tab)[s * 32 + ip];
                            float part = __shfl_xor(v, 1);
                            v = (lr & 1) ? (v * cs.x + part * cs.y)
                                         : (v * cs.x - part * cs.y);
                        }
                        qp[(size_t)r * 2048 + c] = f2bf(v);
                    } else if (c < 2688) {
                        kvp[(size_t)r * KV_W + (c - 2048)] = v;
                    }
                }
            }
    } else {  // EPI == 2: K_all / Vt scatter
        u16* Kall = (u16*)out0;
        u16* Vt   = (u16*)out1;
#pragma unroll
        for (int m = 0; m < 8; ++m) {
            int r0 = row0 + wr * 128 + m * 16 + 4 * lg;
            int b  = r0 >> 11;
            int s0 = r0 & (SEQ - 1);
#pragma unroll
            for (int n = 0; n < 4; ++n) {
                int c = col0 + wc * 64 + n * 16 + lr;
                int h = (unsigned)c / 192u;
                int cr = c - h * 192;
                int bh = b * NHEAD + h;
                if (cr < 64) {
#pragma unroll
                    for (int j = 0; j < 4; ++j) {
                        int s = s0 + j;
                        Kall[((size_t)bh * SEQ + s) * 128 + (cr ^ ((s & 7) << 3))] = f2bf(acc[m][n][j]);
                    }
                } else {
                    int d = cr - 64;
                    union { u16 u[4]; uint2 v; } pk;
#pragma unroll
                    for (int j = 0; j < 4; ++j) pk.u[j] = f2bf(acc[m][n][j]);
                    size_t base = ((size_t)bh * 128 + d) * SEQ + (s0 & ~63);
                    *(uint2*)&Vt[base + ((s0 & 63) ^ ((d & 7) << 3))] = pk.v;
                }
            }
        }
    }
}

// ============ 256x128 variant (fp32 out), 3-deep pipeline, vmcnt(6) =========
__global__ __launch_bounds__(512, 1) void gemm_out(const u16* __restrict__ A,
                                                   const u16* __restrict__ BT,
                                                   float* __restrict__ C,
                                                   int N, int K) {
    __shared__ u16 lds[73728];  // 144KB: A 3buf x 2half x 8192, B 3buf x 8192
    const int tid = threadIdx.x;
    const int w = tid >> 6, l = tid & 63;
    const int lr = l & 15, lg = l >> 4;
    const int wr = w >> 1, wc = w & 1;       // 4M x 2N waves, 64x64 each
    const int nwg = gridDim.x, q8 = nwg >> 3;
    const int wg = (blockIdx.x & 7) * q8 + (blockIdx.x >> 3);
    const int gx = N >> 7;
    const int row0 = (wg / gx) * 256, col0 = (wg % gx) * 128;
    const int NT = K >> 6;

    f32x4 acc[4][4];
#pragma unroll
    for (int m = 0; m < 4; ++m)
#pragma unroll
        for (int n = 0; n < 4; ++n) acc[m][n] = (f32x4){0.f, 0.f, 0.f, 0.f};

    auto stageA = [&](int bufi, int h, int kt) {
        u16* base = lds + bufi * 16384 + h * 8192;
        const u16* g = A + (size_t)(row0 + h * 128) * K + kt * 64;
#pragma unroll
        for (int i = 0; i < 2; ++i) {
            int L = (i * 512 + tid) * 16;
            int s = L ^ (((L >> 7) & 7) << 4);
            gload16(g + (size_t)(s >> 7) * K + ((s & 127) >> 1), base + (L >> 1));
        }
    };
    auto stageB = [&](int bufi, int kt) {
        u16* base = lds + 49152 + bufi * 8192;
        const u16* g = BT + (size_t)col0 * K + kt * 64;
#pragma unroll
        for (int i = 0; i < 2; ++i) {
            int L = (i * 512 + tid) * 16;
            int s = L ^ (((L >> 7) & 7) << 4);
            gload16(g + (size_t)(s >> 7) * K + ((s & 127) >> 1), base + (L >> 1));
        }
    };

    // prologue: tiles 0 and 1 (6 loads each)
    stageA(0, 0, 0); stageA(0, 1, 0); stageB(0, 0);
    stageA(1, 0, 1); stageA(1, 1, 1); stageB(1, 1);

    const int ar0 = (wr & 1) * 64;

    for (int t = 0; t < NT; ++t) {
        const int buf = t % 3, nb2 = (t + 2) % 3;
        u16* Ab = lds + buf * 16384 + (wr >> 1) * 8192;
        u16* Bb = lds + 49152 + buf * 8192;
        if (t + 1 < NT) asm volatile("s_waitcnt vmcnt(6)" ::: "memory");
        else            asm volatile("s_waitcnt vmcnt(0)" ::: "memory");
        __builtin_amdgcn_s_barrier();
        __builtin_amdgcn_sched_barrier(0);

#pragma unroll
        for (int q = 0; q < 2; ++q) {        // phase = k-slice
            bf16x8 af[4], bfg[4];
#pragma unroll
            for (int i = 0; i < 4; ++i) {
                int row = ar0 + i * 16 + lr;
                int byte = row * 128 + q * 64 + lg * 16;
                af[i] = *(const bf16x8*)&Ab[(byte ^ ((row & 7) << 4)) >> 1];
            }
#pragma unroll
            for (int n = 0; n < 4; ++n) {
                int row = wc * 64 + n * 16 + lr;
                int byte = row * 128 + q * 64 + lg * 16;
                bfg[n] = *(const bf16x8*)&Bb[(byte ^ ((row & 7) << 4)) >> 1];
            }
            if (t + 2 < NT) {
                if (q == 0) { stageA(nb2, 0, t + 2); stageA(nb2, 1, t + 2); }
                else        { stageB(nb2, t + 2); }
            }
            __builtin_amdgcn_s_barrier();
            asm volatile("s_waitcnt lgkmcnt(0)" ::: "memory");
            __builtin_amdgcn_sched_barrier(0);
            __builtin_amdgcn_s_setprio(1);
#pragma unroll
            for (int i = 0; i < 4; ++i)
#pragma unroll
                for (int n = 0; n < 4; ++n)
                    acc[i][n] = __builtin_amdgcn_mfma_f32_16x16x32_bf16(
                        af[i], bfg[n], acc[i][n], 0, 0, 0);
            __builtin_amdgcn_s_setprio(0);
        }
    }

#pragma unroll
    for (int m = 0; m < 4; ++m)
#pragma unroll
        for (int n = 0; n < 4; ++n) {
            int c = col0 + wc * 64 + n * 16 + lr;
#pragma unroll
            for (int j = 0; j < 4; ++j) {
                int r = row0 + wr * 64 + m * 16 + 4 * lg + j;
                C[(size_t)r * N + c] = acc[m][n][j];
            }
        }
}

// -------- RMS norm + fused k_pe build: one block per (b,s) row --------------
__global__ __launch_bounds__(256) void rmsnorm_bf(const float* __restrict__ kv,
                                                  const float* __restrict__ w,
                                                  u16* __restrict__ c_norm,
                                                  const float* __restrict__ tab,
                                                  u16* __restrict__ K_all) {
    __shared__ float red[256];
    const int row = blockIdx.x, t = threadIdx.x;
    const float* src = kv + (size_t)row * KV_W;
    float v0 = src[t], v1 = src[t + 256];
    red[t] = v0 * v0 + v1 * v1;
    __syncthreads();
    for (int s = 128; s > 0; s >>= 1) {
        if (t < s) red[t] += red[t + s];
        __syncthreads();
    }
    const float inv = rsqrtf(red[0] / (float)KV_RANK + EPS_F);
    u16* dst = c_norm + (size_t)row * KV_RANK;
    dst[t]       = f2bf(v0 * inv * w[t]);
    dst[t + 256] = f2bf(v1 * inv * w[t + 256]);

    if (t < 16) {  // fused k_pe: rope kv[512..575] -> 16 head slices
        const int dq = t;
        const int s = row & (SEQ - 1);
        const int b = row >> 11;
        float4 v = *(const float4*)(src + KV_RANK + 4 * dq);
        const int i0 = 2 * dq;
        float2 cs0 = ((const float2*)tab)[s * 32 + i0];
        float2 cs1 = ((const float2*)tab)[s * 32 + i0 + 1];
        union { u16 u[4]; uint2 w2; } pk;
        pk.u[0] = f2bf(v.x * cs0.x - v.y * cs0.y);
        pk.u[1] = f2bf(v.y * cs0.x + v.x * cs0.y);
        pk.u[2] = f2bf(v.z * cs1.x - v.w * cs1.y);
        pk.u[3] = f2bf(v.w * cs1.x + v.z * cs1.y);
        const int idx = (64 + 4 * dq) ^ ((s & 7) << 3);
#pragma unroll
        for (int h = 0; h < NHEAD; ++h) {
            int bh = b * NHEAD + h;
            *(uint2*)&K_all[((size_t)bh * SEQ + s) * 128 + idx] = pk.w2;
        }
    }
}

// ---------------- flash attention: QTILE=128, pair-balanced -----------------
// 512 thr (8 waves), per-wave 16 q-rows. Units of 128 q-rows; block handles
// (15-pi, pi) -> uniform 34 K-tiles/block. Grid 256 = exact 1 block/CU.
// One K/V stage serves 128 q-rows (half the staging per unit work vs QTILE=64).
#define QTILE 128
#define KTILE 64

__global__ __launch_bounds__(512, 1) void attn_mfma(const u16* __restrict__ q_bf,
                                                    const u16* __restrict__ K_all,
                                                    const u16* __restrict__ Vt,
                                                    u16* __restrict__ attn_bf) {
    __shared__ u16 Kbuf[2][KTILE * 128];   // 2 x 16KB
    __shared__ u16 Vbuf[2][128 * KTILE];   // 2 x 16KB
    __shared__ u16 Plds[8][16 * KTILE];    // 16KB, wave-private

    const int idx = blockIdx.x;                       // 0..255
    const int bh = (idx & 7) + 8 * (idx >> 6);        // 4 heads per XCD (L2-fit)
    const int pi = (idx >> 3) & 7;                    // pair index 0..7
    const int b = bh >> 4, h = bh & 15;

    const int tid = threadIdx.x;
    const int w = tid >> 6, l = tid & 63;
    const int lr = l & 15, lg = l >> 4;
    const u16* Kb = K_all + (size_t)bh * SEQ * 128;
    const u16* Vb = Vt + (size_t)bh * 128 * SEQ;
    const int sw = (lr & 7) << 3;                     // u16-index XOR
    u16* pw = Plds[w];

    auto stage = [&](int bufi, int k0) {
        u16* kb = Kbuf[bufi];
        u16* vb = Vbuf[bufi];
#pragma unroll
        for (int it = 0; it < 2; ++it) {              // K: 1024 x 16B chunks
            int ci = it * 512 + tid;
            gload16(Kb + (((size_t)(k0 + (ci >> 4))) << 7) + ((ci & 15) << 3),
                    kb + (ci << 3));
        }
#pragma unroll
        for (int it = 0; it < 2; ++it) {              // V: 1024 x 16B chunks
            int ci = it * 512 + tid;
            gload16(Vb + (size_t)(ci >> 3) * SEQ + k0 + ((ci & 7) << 3),
                    vb + (ci << 3));
        }
    };

    const int qbA = (15 - pi) * QTILE;
    const int qbB = pi * QTILE;

    stage(0, 0);
    int cur = 0;
    for (int half = 0; half < 2; ++half) {
        const int qbase = half ? qbB : qbA;
        const int nkt = (qbase >> 6) + 2;
        const int qg = qbase + 16 * w + lr;

        const u16* qrow = q_bf + (size_t)(b * SEQ + qg) * 2048 + h * QK_HEAD;
        bf16x8 qf[4];
#pragma unroll
        for (int dc = 0; dc < 4; ++dc) qf[dc] = *(const bf16x8*)(qrow + dc * 32 + lg * 8);

        f32x4 oacc[8];
#pragma unroll
        for (int ft = 0; ft < 8; ++ft) oacc[ft] = (f32x4){0.f, 0.f, 0.f, 0.f};
        float m_r = -1e30f, l_r = 0.f;

        for (int kt = 0; kt < nkt; ++kt) {
            const int k0 = kt * KTILE;
            if (kt + 1 < nkt) {
                stage(cur ^ 1, k0 + KTILE);
                asm volatile("s_waitcnt vmcnt(4)" ::: "memory");
            } else if (half == 0) {
                stage(cur ^ 1, 0);                    // prefetch half-B tile 0
                asm volatile("s_waitcnt vmcnt(4)" ::: "memory");
            } else {
                asm volatile("s_waitcnt vmcnt(0)" ::: "memory");
            }
            __builtin_amdgcn_s_barrier();
            __builtin_amdgcn_sched_barrier(0);

            if (k0 <= qbase + 16 * w + 15) {          // wave-uniform skip
                const u16* kb = Kbuf[cur];
                const u16* vb = Vbuf[cur];

                // ---- S^T = K @ Q^T ----
                f32x4 s[4];
                __builtin_amdgcn_s_setprio(1);
#pragma unroll
                for (int f = 0; f < 4; ++f) {
                    s[f] = (f32x4){0.f, 0.f, 0.f, 0.f};
#pragma unroll
                    for (int dc = 0; dc < 4; ++dc) {
                        bf16x8 kf = *(const bf16x8*)&kb[(16 * f + lr) * 128 + ((32 * dc + 8 * lg) ^ sw)];
                        s[f] = __builtin_amdgcn_mfma_f32_16x16x32_bf16(kf, qf[dc], s[f], 0, 0, 0);
                    }
                }
                __builtin_amdgcn_s_setprio(0);

                // ---- causal mask (diagonal region only) ----
                if (k0 + KTILE - 1 > qbase + 16 * w) {
#pragma unroll
                    for (int f = 0; f < 4; ++f)
#pragma unroll
                        for (int j = 0; j < 4; ++j)
                            if (k0 + 16 * f + 4 * lg + j > qg) s[f][j] = -1e30f;
                }

                // ---- online softmax (log2 domain), defer-max, asm exp2 ----
                float t0 = fmaxf(fmaxf(s[0][0], s[0][1]), fmaxf(s[0][2], s[0][3]));
                float t1 = fmaxf(fmaxf(s[1][0], s[1][1]), fmaxf(s[1][2], s[1][3]));
                float t2 = fmaxf(fmaxf(s[2][0], s[2][1]), fmaxf(s[2][2], s[2][3]));
                float t3 = fmaxf(fmaxf(s[3][0], s[3][1]), fmaxf(s[3][2], s[3][3]));
                float t = fmaxf(fmaxf(t0, t1), fmaxf(t2, t3));
                t = fmaxf(t, __shfl_xor(t, 16));
                t = fmaxf(t, __shfl_xor(t, 32));
                bool up = (t > m_r + 11.5f);          // 2^11.5 headroom
                float newm = up ? t : m_r;
                float sf_ = up ? exp2_hw(m_r - t) : 1.0f;
                m_r = newm;
                float rs = 0.f;
#pragma unroll
                for (int f = 0; f < 4; ++f)
#pragma unroll
                    for (int j = 0; j < 4; ++j) {
                        float p = exp2_hw(s[f][j] - newm);
                        s[f][j] = p;
                        rs += p;
                    }
                rs += __shfl_xor(rs, 16);
                rs += __shfl_xor(rs, 32);
                l_r = l_r * sf_ + rs;
                if (__any(up)) {
#pragma unroll
                    for (int ft = 0; ft < 8; ++ft)
#pragma unroll
                        for (int j = 0; j < 4; ++j) oacc[ft][j] *= sf_;
                }

                // ---- P -> wave-private LDS, re-layout to B-fragment ----
#pragma unroll
                for (int f = 0; f < 4; ++f) {
                    union { u16 u[4]; uint2 v; } pk;
#pragma unroll
                    for (int j = 0; j < 4; ++j) pk.u[j] = f2bf(s[f][j]);
                    *(uint2*)&pw[lr * 64 + ((16 * f + 4 * lg) ^ sw)] = pk.v;
                }
                asm volatile("s_waitcnt lgkmcnt(0)" ::: "memory");
                bf16x8 pfr[2];
#pragma unroll
                for (int ks = 0; ks < 2; ++ks)
                    pfr[ks] = *(const bf16x8*)&pw[lr * 64 + ((32 * ks + 8 * lg) ^ sw)];

                // ---- O^T += V^T @ P^T ----
                __builtin_amdgcn_s_setprio(1);
#pragma unroll
                for (int ft = 0; ft < 8; ++ft) {
                    int d = 16 * ft + lr;
#pragma unroll
                    for (int ks = 0; ks < 2; ++ks) {
                        bf16x8 vf = *(const bf16x8*)&vb[d * 64 + ((32 * ks + 8 * lg) ^ sw)];
                        oacc[ft] = __builtin_amdgcn_mfma_f32_16x16x32_bf16(vf, pfr[ks], oacc[ft], 0, 0, 0);
                    }
                }
                __builtin_amdgcn_s_setprio(0);
            }
            __builtin_amdgcn_s_barrier();
            cur ^= 1;
        }

        // ---- epilogue for this half ----
        const float inv = 1.0f / l_r;
        u16* orow = attn_bf + (size_t)(b * SEQ + qg) * 2048 + h * V_HEAD;
#pragma unroll
        for (int ft = 0; ft < 8; ++ft) {
            union { u16 u[4]; uint2 v; } ok;
#pragma unroll
            for (int j = 0; j < 4; ++j) ok.u[j] = f2bf(oacc[ft][j] * inv);
            *(uint2*)(orow + 16 * ft + 4 * lg) = ok.v;
        }
    }
}

// ------------------------------------------------------------------
extern "C" void kernel_launch(void* const* d_in, const int* in_sizes, int n_in,
                              void* d_out, int out_size, void* d_ws, size_t ws_size,
                              hipStream_t stream) {
    const float* x         = (const float*)d_in[0];
    const float* w_query   = (const float*)d_in[1];
    const float* wkv_a     = (const float*)d_in[2];
    const float* wkv_b     = (const float*)d_in[3];
    const float* kv_norm_w = (const float*)d_in[4];
    const float* out_proj  = (const float*)d_in[5];

    u16* x_bf     = (u16*)d_ws;                       // 8M u16 (aliased by attn_bf)
    u16* q_bf     = x_bf + (size_t)8388608;           // 8M
    u16* c_norm   = q_bf + (size_t)8388608;           // 2M
    u16* kvdec_bf = c_norm + (size_t)2097152;         // (unused)
    u16* K_all    = kvdec_bf + (size_t)12582912;      // 8.39M
    u16* Vt       = K_all + (size_t)8388608;          // 8.39M
    u16* wT       = Vt + (size_t)8388608;             // wqT(4M) + wkvaT(1.31M) contiguous
    u16* wkvaT    = wT + (size_t)4194304;
    u16* wkvbT    = wkvaT + (size_t)1310720;          // 1.57M
    u16* opT      = wkvbT + (size_t)1572864;          // 4M
    float* kv     = (float*)(opT + (size_t)4194304);  // 2.62M floats
    float* tab    = kv + (size_t)2621440;             // 131072 floats
    u16* attn_bf  = x_bf;                             // alias (x_bf dead after merged GEMM)
    float* out = (float*)d_out;

    // 128^-0.5 * log2(e): QK scale + exp->exp2 conversion folded into q
    const float qscale2 = 0.08838834764831845f * 1.4426950408889634f;

    prep<<<19456, 256, 0, stream>>>(x, x_bf, w_query, wT, wkv_a, wkvaT,
                                    wkv_b, wkvbT, out_proj, opT, tab);

    // merged q + kv GEMM: N = 2688 (11 col tiles), fused RoPE(q) epilogue
    gemm256<0><<<176, 512, 0, stream>>>(x_bf, wT, q_bf, kv, tab,
                                        11, 2688, 2048, qscale2);
    rmsnorm_bf<<<NTOK, 256, 0, stream>>>(kv, kv_norm_w, c_norm, tab, K_all);
    // wkv_b GEMM with fused K_all/Vt scatter epilogue
    gemm256<2><<<192, 512, 0, stream>>>(c_norm, wkvbT, K_all, Vt, nullptr,
                                        12, 3072, 512, 1.0f);

    attn_mfma<<<256, 512, 0, stream>>>(q_bf, K_all, Vt, attn_bf);

    gemm_out<<<256, 512, 0, stream>>>(attn_bf, opT, out, 2048, 2048);
}

// Round 13
// 228.386 us; speedup vs baseline: 1.1082x; 1.1082x over previous
//
#include <hip/hip_runtime.h>
#include <hip/hip_bf16.h>
#include <math.h>

#define BATCH   2
#define SEQ     2048
#define D_IN    2048
#define NHEAD   16
#define QK_ROPE 64
#define QK_NOPE 64
#define QK_HEAD 128
#define V_HEAD  128
#define KV_RANK 512
#define KV_W    640          // kv row stride (576 padded to 640)
#define NTOK    (BATCH*SEQ)  // 4096
#define EPS_F   1e-6f

typedef unsigned short u16;
typedef short bf16x8 __attribute__((ext_vector_type(8)));
typedef float f32x4  __attribute__((ext_vector_type(4)));

__device__ __forceinline__ u16 f2bf(float f) {
    unsigned u = __float_as_uint(f);
    return (u16)((u + 0x7fffu + ((u >> 16) & 1u)) >> 16);
}
__device__ __forceinline__ float bf2f(u16 u) {
    return __uint_as_float(((unsigned)u) << 16);
}
__device__ __forceinline__ float exp2_hw(float x) {
    float r;
    asm volatile("v_exp_f32 %0, %1\n\ts_nop 0" : "=v"(r) : "v"(x));
    return r;
}
__device__ __forceinline__ void gload16(const void* g, void* l) {
    __builtin_amdgcn_global_load_lds((const __attribute__((address_space(1))) unsigned int*)g,
                                     (__attribute__((address_space(3))) unsigned int*)l, 16, 0, 0);
}

// ---------------- fused preamble: convert + 4 transposes + rope table -------
__device__ __forceinline__ void transpose_sec(const float* __restrict__ src,
                                              u16* __restrict__ dst,
                                              int N, int K, int bx, int by,
                                              float (*tile)[33], int tid) {
    const int tx = tid & 31, ty = tid >> 5;
    const int nb = bx * 32, kb = by * 32;
#pragma unroll
    for (int i = 0; i < 4; ++i) {
        int k = kb + ty + 8 * i, n = nb + tx;
        tile[ty + 8 * i][tx] = (n < N) ? src[(size_t)k * N + n] : 0.f;
    }
    __syncthreads();
#pragma unroll
    for (int i = 0; i < 4; ++i) {
        int n = nb + ty + 8 * i, k = kb + tx;
        dst[(size_t)n * K + k] = f2bf(tile[tx][ty + 8 * i]);
    }
}

__global__ __launch_bounds__(256) void prep(const float* __restrict__ x, u16* __restrict__ x_bf,
                                            const float* __restrict__ wq, u16* __restrict__ wqT,
                                            const float* __restrict__ wkva, u16* __restrict__ wkvaT,
                                            const float* __restrict__ wkvb, u16* __restrict__ wkvbT,
                                            const float* __restrict__ op, u16* __restrict__ opT,
                                            float* __restrict__ tab) {
    __shared__ float tile[32][33];
    const int idx = blockIdx.x;
    const int tid = threadIdx.x;
    if (idx < 8192) {                      // x fp32 -> bf16, 4/thread
        int gid = idx * 256 + tid;
        float4 v = ((const float4*)x)[gid];
        unsigned lo = (unsigned)f2bf(v.x) | ((unsigned)f2bf(v.y) << 16);
        unsigned hi = (unsigned)f2bf(v.z) | ((unsigned)f2bf(v.w) << 16);
        ((uint2*)x_bf)[gid] = make_uint2(lo, hi);
    } else if (idx < 12288) {              // w_query^T
        int s = idx - 8192;
        transpose_sec(wq, wqT, 2048, 2048, s % 64, s / 64, tile, tid);
    } else if (idx < 13568) {              // wkv_a^T (576 -> pad 640)
        int s = idx - 12288;
        transpose_sec(wkva, wkvaT, 576, 2048, s % 20, s / 20, tile, tid);
    } else if (idx < 15104) {              // wkv_b^T
        int s = idx - 13568;
        transpose_sec(wkvb, wkvbT, 3072, 512, s % 96, s / 96, tile, tid);
    } else if (idx < 19200) {              // out_proj^T
        int s = idx - 15104;
        transpose_sec(op, opT, 2048, 2048, s % 64, s / 64, tile, tid);
    } else {                               // rope cos/sin table
        int gid = (idx - 19200) * 256 + tid;  // < SEQ*32
        int i = gid & 31, s = gid >> 5;
        float freq = __expf(-(float)(2 * i) / 64.0f * 9.210340371976184f);
        float ang = (float)s * freq;
        tab[2 * gid]     = cosf(ang);
        tab[2 * gid + 1] = sinf(ang);
    }
}

// ============ 128x128 bf16 GEMM, BK=32, 3-buf 2-tile-deep, 3 blocks/CU ======
// 256 thr = 4 waves (2M x 2N), per-wave 64x64, acc[4][4]. LDS 48KB -> 3
// resident blocks/CU (cross-block stall hiding, m103 mechanism) + 2-tile-deep
// prefetch with counted vmcnt(4). ONE barrier per K-tile:
//   [vmcnt(4)][s_barrier][8 ds_read + stage t+2 (4 gloads)][lgkmcnt(0)][16 MFMA]
// Safety: stage(t+2) writes buffer (t+2)%3 == (t-1)%3, whose readers all
// passed the tile-top barrier (their lgkmcnt(0) preceded barrier arrival).
// Swizzle: 64B rows, slot ^= (row^(row>>2))&3, both sides (inverse-swizzled
// global source; swizzled ds_read).
template <int EPI>
__global__ __launch_bounds__(256, 3) void gemm128(const u16* __restrict__ A,
                                                  const u16* __restrict__ BT,
                                                  void* __restrict__ out0,
                                                  void* __restrict__ out1,
                                                  const float* __restrict__ tab,
                                                  int gx, int N, int K, float oscale) {
    __shared__ u16 lds[24576];  // 48KB: A 3x8KB @0, B 3x8KB @12288 (u16 idx)
    const int tid = threadIdx.x;
    const int w = tid >> 6, l = tid & 63;
    const int lr = l & 15, lg = l >> 4;
    const int wr = w >> 1, wc = w & 1;
    const int nwg = gridDim.x, q8 = nwg >> 3;
    const int wg = (blockIdx.x & 7) * q8 + (blockIdx.x >> 3);
    const int row0 = (wg / gx) * 128, col0 = (wg % gx) * 128;
    const int NT = K >> 5;

    f32x4 acc[4][4];
#pragma unroll
    for (int m = 0; m < 4; ++m)
#pragma unroll
        for (int n = 0; n < 4; ++n) acc[m][n] = (f32x4){0.f, 0.f, 0.f, 0.f};

    // stage 128x32 k-tile (8KB, 2 gloads/thread)
    auto stageA = [&](int bufi, int kt) {
        u16* base = lds + bufi * 4096;
        const u16* g = A + (size_t)row0 * K + kt * 32;
#pragma unroll
        for (int i = 0; i < 2; ++i) {
            int L = (i * 256 + tid) * 16;                 // linear LDS byte
            int f = ((L >> 6) ^ (L >> 8)) & 3;
            int s = L ^ (f << 4);                         // inverse-swizzled src
            gload16(g + (size_t)(L >> 6) * K + ((s & 63) >> 1), base + (L >> 1));
        }
    };
    auto stageB = [&](int bufi, int kt) {
        u16* base = lds + 12288 + bufi * 4096;
        const u16* g = BT + (size_t)col0 * K + kt * 32;
#pragma unroll
        for (int i = 0; i < 2; ++i) {
            int L = (i * 256 + tid) * 16;
            int f = ((L >> 6) ^ (L >> 8)) & 3;
            int s = L ^ (f << 4);
            gload16(g + (size_t)(L >> 6) * K + ((s & 63) >> 1), base + (L >> 1));
        }
    };

    // prologue: tiles 0 and 1 (4 loads each, oldest-first)
    stageA(0, 0); stageB(0, 0); stageA(1, 1); stageB(1, 1);

    for (int t = 0; t < NT; ++t) {
        const int buf = t % 3, nb2 = (t + 2) % 3;
        u16* Ab = lds + buf * 4096;
        u16* Bb = lds + 12288 + buf * 4096;
        if (t + 1 < NT) asm volatile("s_waitcnt vmcnt(4)" ::: "memory");
        else            asm volatile("s_waitcnt vmcnt(0)" ::: "memory");
        __builtin_amdgcn_s_barrier();
        __builtin_amdgcn_sched_barrier(0);

        bf16x8 af[4], bfg[4];
#pragma unroll
        for (int n = 0; n < 4; ++n) {
            int row = wc * 64 + n * 16 + lr;
            int fr = (row ^ (row >> 2)) & 3;
            bfg[n] = *(const bf16x8*)&Bb[(row * 64 + ((lg ^ fr) << 4)) >> 1];
        }
#pragma unroll
        for (int i = 0; i < 4; ++i) {
            int row = wr * 64 + i * 16 + lr;
            int fr = (row ^ (row >> 2)) & 3;
            af[i] = *(const bf16x8*)&Ab[(row * 64 + ((lg ^ fr) << 4)) >> 1];
        }
        if (t + 2 < NT) { stageA(nb2, t + 2); stageB(nb2, t + 2); }
        asm volatile("s_waitcnt lgkmcnt(0)" ::: "memory");
        __builtin_amdgcn_sched_barrier(0);
        __builtin_amdgcn_s_setprio(1);
#pragma unroll
        for (int i = 0; i < 4; ++i)
#pragma unroll
            for (int n = 0; n < 4; ++n)
                acc[i][n] = __builtin_amdgcn_mfma_f32_16x16x32_bf16(af[i], bfg[n], acc[i][n], 0, 0, 0);
        __builtin_amdgcn_s_setprio(0);
    }

    // ---- epilogues: row = row0+wr*64+m*16+4lg+j, col = col0+wc*64+n*16+lr --
    if (EPI == 0) {
        u16* qp = (u16*)out0;
        float* kvp = (float*)out1;
        const bool pe = (wc == 1);  // head-offset >= 64 -> rope half
#pragma unroll
        for (int m = 0; m < 4; ++m)
#pragma unroll
            for (int n = 0; n < 4; ++n) {
                int c = col0 + wc * 64 + n * 16 + lr;
#pragma unroll
                for (int j = 0; j < 4; ++j) {
                    int r = row0 + wr * 64 + m * 16 + 4 * lg + j;
                    float v = acc[m][n][j];
                    if (c < 2048) {
                        v *= oscale;
                        if (pe) {
                            int s = r & (SEQ - 1);
                            int ip = (16 * n + lr) >> 1;
                            float2 cs = ((const float2*)tab)[s * 32 + ip];
                            float part = __shfl_xor(v, 1);
                            v = (lr & 1) ? (v * cs.x + part * cs.y)
                                         : (v * cs.x - part * cs.y);
                        }
                        qp[(size_t)r * 2048 + c] = f2bf(v);
                    } else {
                        kvp[(size_t)r * KV_W + (c - 2048)] = v;
                    }
                }
            }
    } else if (EPI == 1) {
        float* C = (float*)out0;
#pragma unroll
        for (int m = 0; m < 4; ++m)
#pragma unroll
            for (int n = 0; n < 4; ++n) {
                int c = col0 + wc * 64 + n * 16 + lr;
#pragma unroll
                for (int j = 0; j < 4; ++j) {
                    int r = row0 + wr * 64 + m * 16 + 4 * lg + j;
                    C[(size_t)r * N + c] = acc[m][n][j];
                }
            }
    } else {  // EPI == 2: K_all / Vt scatter
        u16* Kall = (u16*)out0;
        u16* Vt   = (u16*)out1;
#pragma unroll
        for (int m = 0; m < 4; ++m) {
            int r0 = row0 + wr * 64 + m * 16 + 4 * lg;
            int b  = r0 >> 11;
            int s0 = r0 & (SEQ - 1);
#pragma unroll
            for (int n = 0; n < 4; ++n) {
                int c = col0 + wc * 64 + n * 16 + lr;
                int h = (unsigned)c / 192u;
                int cr = c - h * 192;
                int bh = b * NHEAD + h;
                if (cr < 64) {
#pragma unroll
                    for (int j = 0; j < 4; ++j) {
                        int s = s0 + j;
                        Kall[((size_t)bh * SEQ + s) * 128 + (cr ^ ((s & 7) << 3))] = f2bf(acc[m][n][j]);
                    }
                } else {
                    int d = cr - 64;
                    union { u16 u[4]; uint2 v; } pk;
#pragma unroll
                    for (int j = 0; j < 4; ++j) pk.u[j] = f2bf(acc[m][n][j]);
                    size_t base = ((size_t)bh * 128 + d) * SEQ + (s0 & ~63);
                    *(uint2*)&Vt[base + ((s0 & 63) ^ ((d & 7) << 3))] = pk.v;
                }
            }
        }
    }
}

// -------- RMS norm + fused k_pe build: one block per (b,s) row --------------
__global__ __launch_bounds__(256) void rmsnorm_bf(const float* __restrict__ kv,
                                                  const float* __restrict__ w,
                                                  u16* __restrict__ c_norm,
                                                  const float* __restrict__ tab,
                                                  u16* __restrict__ K_all) {
    __shared__ float red[256];
    const int row = blockIdx.x, t = threadIdx.x;
    const float* src = kv + (size_t)row * KV_W;
    float v0 = src[t], v1 = src[t + 256];
    red[t] = v0 * v0 + v1 * v1;
    __syncthreads();
    for (int s = 128; s > 0; s >>= 1) {
        if (t < s) red[t] += red[t + s];
        __syncthreads();
    }
    const float inv = rsqrtf(red[0] / (float)KV_RANK + EPS_F);
    u16* dst = c_norm + (size_t)row * KV_RANK;
    dst[t]       = f2bf(v0 * inv * w[t]);
    dst[t + 256] = f2bf(v1 * inv * w[t + 256]);

    if (t < 16) {  // fused k_pe: rope kv[512..575] -> 16 head slices
        const int dq = t;
        const int s = row & (SEQ - 1);
        const int b = row >> 11;
        float4 v = *(const float4*)(src + KV_RANK + 4 * dq);
        const int i0 = 2 * dq;
        float2 cs0 = ((const float2*)tab)[s * 32 + i0];
        float2 cs1 = ((const float2*)tab)[s * 32 + i0 + 1];
        union { u16 u[4]; uint2 w2; } pk;
        pk.u[0] = f2bf(v.x * cs0.x - v.y * cs0.y);
        pk.u[1] = f2bf(v.y * cs0.x + v.x * cs0.y);
        pk.u[2] = f2bf(v.z * cs1.x - v.w * cs1.y);
        pk.u[3] = f2bf(v.w * cs1.x + v.z * cs1.y);
        const int idx = (64 + 4 * dq) ^ ((s & 7) << 3);
#pragma unroll
        for (int h = 0; h < NHEAD; ++h) {
            int bh = b * NHEAD + h;
            *(uint2*)&K_all[((size_t)bh * SEQ + s) * 128 + idx] = pk.w2;
        }
    }
}

// ---------------- flash attention: pair-balanced blocks (R11 version) -------
#define QTILE 64
#define KTILE 64

__global__ __launch_bounds__(256, 2) void attn_mfma(const u16* __restrict__ q_bf,
                                                    const u16* __restrict__ K_all,
                                                    const u16* __restrict__ Vt,
                                                    u16* __restrict__ attn_bf) {
    __shared__ u16 Kbuf[2][KTILE * 128];   // 2 x 16KB
    __shared__ u16 Vbuf[2][128 * KTILE];   // 2 x 16KB
    __shared__ u16 Plds[4][16 * KTILE];    // 8KB, wave-private

    const int idx = blockIdx.x;                       // 0..511
    const int bh = (idx & 7) + 8 * (idx >> 7);        // 4 heads per XCD (4MB = L2)
    const int pi = (idx >> 3) & 15;                   // pair index
    const int b = bh >> 4, h = bh & 15;

    const int tid = threadIdx.x;
    const int w = tid >> 6, l = tid & 63;
    const int lr = l & 15, lg = l >> 4;
    const u16* Kb = K_all + (size_t)bh * SEQ * 128;
    const u16* Vb = Vt + (size_t)bh * 128 * SEQ;
    const int sw = (lr & 7) << 3;                     // u16-index XOR
    u16* pw = Plds[w];

    auto stage = [&](int bufi, int k0) {
        u16* kb = Kbuf[bufi];
        u16* vb = Vbuf[bufi];
#pragma unroll
        for (int it = 0; it < 4; ++it) {              // K: 1024 x 16B chunks
            int ci = it * 256 + tid;
            gload16(Kb + (((size_t)(k0 + (ci >> 4))) << 7) + ((ci & 15) << 3),
                    kb + (ci << 3));
        }
#pragma unroll
        for (int it = 0; it < 4; ++it) {              // V: 1024 x 16B chunks
            int ci = it * 256 + tid;
            gload16(Vb + (size_t)(ci >> 3) * SEQ + k0 + ((ci & 7) << 3),
                    vb + (ci << 3));
        }
    };

    const int qbA = (31 - pi) * QTILE;
    const int qbB = pi * QTILE;

    stage(0, 0);
    int cur = 0;
    for (int half = 0; half < 2; ++half) {
        const int qbase = half ? qbB : qbA;
        const int nkt = (qbase >> 6) + 1;
        const int qg = qbase + 16 * w + lr;

        const u16* qrow = q_bf + (size_t)(b * SEQ + qg) * 2048 + h * QK_HEAD;
        bf16x8 qf[4];
#pragma unroll
        for (int dc = 0; dc < 4; ++dc) qf[dc] = *(const bf16x8*)(qrow + dc * 32 + lg * 8);

        f32x4 oacc[8];
#pragma unroll
        for (int ft = 0; ft < 8; ++ft) oacc[ft] = (f32x4){0.f, 0.f, 0.f, 0.f};
        float m_r = -1e30f, l_r = 0.f;

        for (int kt = 0; kt < nkt; ++kt) {
            const int k0 = kt * KTILE;
            if (kt + 1 < nkt) {
                stage(cur ^ 1, k0 + KTILE);
                asm volatile("s_waitcnt vmcnt(8)" ::: "memory");
            } else if (half == 0) {
                stage(cur ^ 1, 0);                    // prefetch half-B tile 0
                asm volatile("s_waitcnt vmcnt(8)" ::: "memory");
            } else {
                asm volatile("s_waitcnt vmcnt(0)" ::: "memory");
            }
            __builtin_amdgcn_s_barrier();
            __builtin_amdgcn_sched_barrier(0);

            const u16* kb = Kbuf[cur];
            const u16* vb = Vbuf[cur];

            // ---- S^T = K @ Q^T ----
            f32x4 s[4];
            __builtin_amdgcn_s_setprio(1);
#pragma unroll
            for (int f = 0; f < 4; ++f) {
                s[f] = (f32x4){0.f, 0.f, 0.f, 0.f};
#pragma unroll
                for (int dc = 0; dc < 4; ++dc) {
                    bf16x8 kf = *(const bf16x8*)&kb[(16 * f + lr) * 128 + ((32 * dc + 8 * lg) ^ sw)];
                    s[f] = __builtin_amdgcn_mfma_f32_16x16x32_bf16(kf, qf[dc], s[f], 0, 0, 0);
                }
            }
            __builtin_amdgcn_s_setprio(0);

            // ---- causal mask (diagonal tile only) ----
            if (kt == nkt - 1) {
#pragma unroll
                for (int f = 0; f < 4; ++f)
#pragma unroll
                    for (int j = 0; j < 4; ++j)
                        if (k0 + 16 * f + 4 * lg + j > qg) s[f][j] = -1e30f;
            }

            // ---- online softmax (log2 domain), defer-max, asm exp2 ----
            float t0 = fmaxf(fmaxf(s[0][0], s[0][1]), fmaxf(s[0][2], s[0][3]));
            float t1 = fmaxf(fmaxf(s[1][0], s[1][1]), fmaxf(s[1][2], s[1][3]));
            float t2 = fmaxf(fmaxf(s[2][0], s[2][1]), fmaxf(s[2][2], s[2][3]));
            float t3 = fmaxf(fmaxf(s[3][0], s[3][1]), fmaxf(s[3][2], s[3][3]));
            float t = fmaxf(fmaxf(t0, t1), fmaxf(t2, t3));
            t = fmaxf(t, __shfl_xor(t, 16));
            t = fmaxf(t, __shfl_xor(t, 32));
            bool up = (t > m_r + 11.5f);              // 2^11.5 headroom
            float newm = up ? t : m_r;
            float sf_ = up ? exp2_hw(m_r - t) : 1.0f;
            m_r = newm;
            float rs = 0.f;
#pragma unroll
            for (int f = 0; f < 4; ++f)
#pragma unroll
                for (int j = 0; j < 4; ++j) {
                    float p = exp2_hw(s[f][j] - newm);
                    s[f][j] = p;
                    rs += p;
                }
            rs += __shfl_xor(rs, 16);
            rs += __shfl_xor(rs, 32);
            l_r = l_r * sf_ + rs;
            if (__any(up)) {
#pragma unroll
                for (int ft = 0; ft < 8; ++ft)
#pragma unroll
                    for (int j = 0; j < 4; ++j) oacc[ft][j] *= sf_;
            }

            // ---- P -> wave-private LDS, re-layout to B-fragment ----
#pragma unroll
            for (int f = 0; f < 4; ++f) {
                union { u16 u[4]; uint2 v; } pk;
#pragma unroll
                for (int j = 0; j < 4; ++j) pk.u[j] = f2bf(s[f][j]);
                *(uint2*)&pw[lr * 64 + ((16 * f + 4 * lg) ^ sw)] = pk.v;
            }
            asm volatile("s_waitcnt lgkmcnt(0)" ::: "memory");
            bf16x8 pfr[2];
#pragma unroll
            for (int ks = 0; ks < 2; ++ks)
                pfr[ks] = *(const bf16x8*)&pw[lr * 64 + ((32 * ks + 8 * lg) ^ sw)];

            // ---- O^T += V^T @ P^T ----
            __builtin_amdgcn_s_setprio(1);
#pragma unroll
            for (int ft = 0; ft < 8; ++ft) {
                int d = 16 * ft + lr;
#pragma unroll
                for (int ks = 0; ks < 2; ++ks) {
                    bf16x8 vf = *(const bf16x8*)&vb[d * 64 + ((32 * ks + 8 * lg) ^ sw)];
                    oacc[ft] = __builtin_amdgcn_mfma_f32_16x16x32_bf16(vf, pfr[ks], oacc[ft], 0, 0, 0);
                }
            }
            __builtin_amdgcn_s_setprio(0);

            __builtin_amdgcn_s_barrier();
            cur ^= 1;
        }

        // ---- epilogue for this half ----
        const float inv = 1.0f / l_r;
        u16* orow = attn_bf + (size_t)(b * SEQ + qg) * 2048 + h * V_HEAD;
#pragma unroll
        for (int ft = 0; ft < 8; ++ft) {
            union { u16 u[4]; uint2 v; } ok;
#pragma unroll
            for (int j = 0; j < 4; ++j) ok.u[j] = f2bf(oacc[ft][j] * inv);
            *(uint2*)(orow + 16 * ft + 4 * lg) = ok.v;
        }
    }
}

// ------------------------------------------------------------------
extern "C" void kernel_launch(void* const* d_in, const int* in_sizes, int n_in,
                              void* d_out, int out_size, void* d_ws, size_t ws_size,
                              hipStream_t stream) {
    const float* x         = (const float*)d_in[0];
    const float* w_query   = (const float*)d_in[1];
    const float* wkv_a     = (const float*)d_in[2];
    const float* wkv_b     = (const float*)d_in[3];
    const float* kv_norm_w = (const float*)d_in[4];
    const float* out_proj  = (const float*)d_in[5];

    u16* x_bf     = (u16*)d_ws;                       // 8M u16 (aliased by attn_bf)
    u16* q_bf     = x_bf + (size_t)8388608;           // 8M
    u16* c_norm   = q_bf + (size_t)8388608;           // 2M
    u16* kvdec_bf = c_norm + (size_t)2097152;         // (unused)
    u16* K_all    = kvdec_bf + (size_t)12582912;      // 8.39M
    u16* Vt       = K_all + (size_t)8388608;          // 8.39M
    u16* wT       = Vt + (size_t)8388608;             // wqT(4M) + wkvaT(1.31M) contiguous
    u16* wkvaT    = wT + (size_t)4194304;
    u16* wkvbT    = wkvaT + (size_t)1310720;          // 1.57M
    u16* opT      = wkvbT + (size_t)1572864;          // 4M
    float* kv     = (float*)(opT + (size_t)4194304);  // 2.62M floats
    float* tab    = kv + (size_t)2621440;             // 131072 floats
    u16* attn_bf  = x_bf;                             // alias (x_bf dead after merged GEMM)
    float* out = (float*)d_out;

    // 128^-0.5 * log2(e): QK scale + exp->exp2 conversion folded into q
    const float qscale2 = 0.08838834764831845f * 1.4426950408889634f;

    prep<<<19456, 256, 0, stream>>>(x, x_bf, w_query, wT, wkv_a, wkvaT,
                                    wkv_b, wkvbT, out_proj, opT, tab);

    // merged q + kv GEMM: N = 2688 = 21 col tiles, fused RoPE(q) epilogue
    gemm128<0><<<672, 256, 0, stream>>>(x_bf, wT, q_bf, kv, tab,
                                        21, 2688, 2048, qscale2);
    rmsnorm_bf<<<NTOK, 256, 0, stream>>>(kv, kv_norm_w, c_norm, tab, K_all);
    // wkv_b GEMM with fused K_all/Vt scatter epilogue: 24 x 32 tiles
    gemm128<2><<<768, 256, 0, stream>>>(c_norm, wkvbT, K_all, Vt, nullptr,
                                        24, 3072, 512, 1.0f);

    attn_mfma<<<512, 256, 0, stream>>>(q_bf, K_all, Vt, attn_bf);

    // out-proj: 16 x 32 tiles
    gemm128<1><<<512, 256, 0, stream>>>(attn_bf, opT, out, nullptr, nullptr,
                                        16, 2048, 2048, 1.0f);
}

// Round 14
// 227.289 us; speedup vs baseline: 1.1135x; 1.0048x over previous
//
#include <hip/hip_runtime.h>
#include <hip/hip_bf16.h>
#include <math.h>

#define BATCH   2
#define SEQ     2048
#define D_IN    2048
#define NHEAD   16
#define QK_ROPE 64
#define QK_NOPE 64
#define QK_HEAD 128
#define V_HEAD  128
#define KV_RANK 512
#define KV_W    640          // kv row stride (576 padded to 640)
#define NTOK    (BATCH*SEQ)  // 4096
#define EPS_F   1e-6f

typedef unsigned short u16;
typedef short bf16x8 __attribute__((ext_vector_type(8)));
typedef float f32x4  __attribute__((ext_vector_type(4)));

__device__ __forceinline__ u16 f2bf(float f) {
    unsigned u = __float_as_uint(f);
    return (u16)((u + 0x7fffu + ((u >> 16) & 1u)) >> 16);
}
__device__ __forceinline__ float bf2f(u16 u) {
    return __uint_as_float(((unsigned)u) << 16);
}
__device__ __forceinline__ float exp2_hw(float x) {
    float r;
    asm volatile("v_exp_f32 %0, %1\n\ts_nop 0" : "=v"(r) : "v"(x));
    return r;
}
__device__ __forceinline__ void gload16(const void* g, void* l) {
    __builtin_amdgcn_global_load_lds((const __attribute__((address_space(1))) unsigned int*)g,
                                     (__attribute__((address_space(3))) unsigned int*)l, 16, 0, 0);
}

// ---------------- fused preamble: convert + 4 transposes + rope table -------
__device__ __forceinline__ void transpose_sec(const float* __restrict__ src,
                                              u16* __restrict__ dst,
                                              int N, int K, int bx, int by,
                                              float (*tile)[33], int tid) {
    const int tx = tid & 31, ty = tid >> 5;
    const int nb = bx * 32, kb = by * 32;
#pragma unroll
    for (int i = 0; i < 4; ++i) {
        int k = kb + ty + 8 * i, n = nb + tx;
        tile[ty + 8 * i][tx] = (n < N) ? src[(size_t)k * N + n] : 0.f;
    }
    __syncthreads();
#pragma unroll
    for (int i = 0; i < 4; ++i) {
        int n = nb + ty + 8 * i, k = kb + tx;
        dst[(size_t)n * K + k] = f2bf(tile[tx][ty + 8 * i]);
    }
}

__global__ __launch_bounds__(256) void prep(const float* __restrict__ x, u16* __restrict__ x_bf,
                                            const float* __restrict__ wq, u16* __restrict__ wqT,
                                            const float* __restrict__ wkva, u16* __restrict__ wkvaT,
                                            const float* __restrict__ wkvb, u16* __restrict__ wkvbT,
                                            const float* __restrict__ op, u16* __restrict__ opT,
                                            float* __restrict__ tab) {
    __shared__ float tile[32][33];
    const int idx = blockIdx.x;
    const int tid = threadIdx.x;
    if (idx < 8192) {                      // x fp32 -> bf16, 4/thread
        int gid = idx * 256 + tid;
        float4 v = ((const float4*)x)[gid];
        unsigned lo = (unsigned)f2bf(v.x) | ((unsigned)f2bf(v.y) << 16);
        unsigned hi = (unsigned)f2bf(v.z) | ((unsigned)f2bf(v.w) << 16);
        ((uint2*)x_bf)[gid] = make_uint2(lo, hi);
    } else if (idx < 12288) {              // w_query^T
        int s = idx - 8192;
        transpose_sec(wq, wqT, 2048, 2048, s % 64, s / 64, tile, tid);
    } else if (idx < 13568) {              // wkv_a^T (576 -> pad 640)
        int s = idx - 12288;
        transpose_sec(wkva, wkvaT, 576, 2048, s % 20, s / 20, tile, tid);
    } else if (idx < 15104) {              // wkv_b^T
        int s = idx - 13568;
        transpose_sec(wkvb, wkvbT, 3072, 512, s % 96, s / 96, tile, tid);
    } else if (idx < 19200) {              // out_proj^T
        int s = idx - 15104;
        transpose_sec(op, opT, 2048, 2048, s % 64, s / 64, tile, tid);
    } else {                               // rope cos/sin table
        int gid = (idx - 19200) * 256 + tid;  // < SEQ*32
        int i = gid & 31, s = gid >> 5;
        float freq = __expf(-(float)(2 * i) / 64.0f * 9.210340371976184f);
        float ang = (float)s * freq;
        tab[2 * gid]     = cosf(ang);
        tab[2 * gid + 1] = sinf(ang);
    }
}

// ============ 128x128 bf16 GEMM, BK=32, 3-buf 2-tile-deep, 3 blocks/CU ======
// 256 thr = 4 waves (2M x 2N), per-wave 64x64, acc[4][4]. Counted vmcnt(4)
// tile-top + single raw s_barrier. NO explicit lgkmcnt/sched_barrier/setprio:
// the compiler interleaves ds_read -> MFMA with fine-grained lgkmcnt(N),
// overlapping the LDS and MFMA pipes within each wave (m97 mechanism).
// Correctness: every ds_read of tile t is consumed by an MFMA before the
// t+1 barrier (compiler-enforced), so stage(t+2)'s overwrite of buf (t-1)%3
// is ordered. Empty asm memory fences pin ops to their barrier interval.
template <int EPI>
__global__ __launch_bounds__(256, 3) void gemm128(const u16* __restrict__ A,
                                                  const u16* __restrict__ BT,
                                                  void* __restrict__ out0,
                                                  void* __restrict__ out1,
                                                  const float* __restrict__ tab,
                                                  int gx, int N, int K, float oscale) {
    __shared__ u16 lds[24576];  // 48KB: A 3x8KB @0, B 3x8KB @12288 (u16 idx)
    const int tid = threadIdx.x;
    const int w = tid >> 6, l = tid & 63;
    const int lr = l & 15, lg = l >> 4;
    const int wr = w >> 1, wc = w & 1;
    const int nwg = gridDim.x, q8 = nwg >> 3;
    const int wg = (blockIdx.x & 7) * q8 + (blockIdx.x >> 3);
    const int row0 = (wg / gx) * 128, col0 = (wg % gx) * 128;
    const int NT = K >> 5;

    f32x4 acc[4][4];
#pragma unroll
    for (int m = 0; m < 4; ++m)
#pragma unroll
        for (int n = 0; n < 4; ++n) acc[m][n] = (f32x4){0.f, 0.f, 0.f, 0.f};

    // stage 128x32 k-tile (8KB, 2 gloads/thread)
    auto stageA = [&](int bufi, int kt) {
        u16* base = lds + bufi * 4096;
        const u16* g = A + (size_t)row0 * K + kt * 32;
#pragma unroll
        for (int i = 0; i < 2; ++i) {
            int L = (i * 256 + tid) * 16;                 // linear LDS byte
            int f = ((L >> 6) ^ (L >> 8)) & 3;
            int s = L ^ (f << 4);                         // inverse-swizzled src
            gload16(g + (size_t)(L >> 6) * K + ((s & 63) >> 1), base + (L >> 1));
        }
    };
    auto stageB = [&](int bufi, int kt) {
        u16* base = lds + 12288 + bufi * 4096;
        const u16* g = BT + (size_t)col0 * K + kt * 32;
#pragma unroll
        for (int i = 0; i < 2; ++i) {
            int L = (i * 256 + tid) * 16;
            int f = ((L >> 6) ^ (L >> 8)) & 3;
            int s = L ^ (f << 4);
            gload16(g + (size_t)(L >> 6) * K + ((s & 63) >> 1), base + (L >> 1));
        }
    };

    // prologue: tiles 0 and 1 (4 loads each, oldest-first)
    stageA(0, 0); stageB(0, 0); stageA(1, 1); stageB(1, 1);

    for (int t = 0; t < NT; ++t) {
        const int buf = t % 3, nb2 = (t + 2) % 3;
        u16* Ab = lds + buf * 4096;
        u16* Bb = lds + 12288 + buf * 4096;
        if (t + 1 < NT) asm volatile("s_waitcnt vmcnt(4)" ::: "memory");
        else            asm volatile("s_waitcnt vmcnt(0)" ::: "memory");
        __builtin_amdgcn_s_barrier();
        asm volatile("" ::: "memory");   // no LDS op may float above the barrier

        bf16x8 af[4], bfg[4];
#pragma unroll
        for (int n = 0; n < 4; ++n) {
            int row = wc * 64 + n * 16 + lr;
            int fr = (row ^ (row >> 2)) & 3;
            bfg[n] = *(const bf16x8*)&Bb[(row * 64 + ((lg ^ fr) << 4)) >> 1];
        }
#pragma unroll
        for (int i = 0; i < 4; ++i) {
            int row = wr * 64 + i * 16 + lr;
            int fr = (row ^ (row >> 2)) & 3;
            af[i] = *(const bf16x8*)&Ab[(row * 64 + ((lg ^ fr) << 4)) >> 1];
        }
        if (t + 2 < NT) { stageA(nb2, t + 2); stageB(nb2, t + 2); }
#pragma unroll
        for (int i = 0; i < 4; ++i)
#pragma unroll
            for (int n = 0; n < 4; ++n)
                acc[i][n] = __builtin_amdgcn_mfma_f32_16x16x32_bf16(af[i], bfg[n], acc[i][n], 0, 0, 0);
    }

    // ---- epilogues: row = row0+wr*64+m*16+4lg+j, col = col0+wc*64+n*16+lr --
    if (EPI == 0) {
        u16* qp = (u16*)out0;
        float* kvp = (float*)out1;
        const bool pe = (wc == 1);  // head-offset >= 64 -> rope half
#pragma unroll
        for (int m = 0; m < 4; ++m)
#pragma unroll
            for (int n = 0; n < 4; ++n) {
                int c = col0 + wc * 64 + n * 16 + lr;
#pragma unroll
                for (int j = 0; j < 4; ++j) {
                    int r = row0 + wr * 64 + m * 16 + 4 * lg + j;
                    float v = acc[m][n][j];
                    if (c < 2048) {
                        v *= oscale;
                        if (pe) {
                            int s = r & (SEQ - 1);
                            int ip = (16 * n + lr) >> 1;
                            float2 cs = ((const float2*)tab)[s * 32 + ip];
                            float part = __shfl_xor(v, 1);
                            v = (lr & 1) ? (v * cs.x + part * cs.y)
                                         : (v * cs.x - part * cs.y);
                        }
                        qp[(size_t)r * 2048 + c] = f2bf(v);
                    } else {
                        kvp[(size_t)r * KV_W + (c - 2048)] = v;
                    }
                }
            }
    } else if (EPI == 1) {
        float* C = (float*)out0;
#pragma unroll
        for (int m = 0; m < 4; ++m)
#pragma unroll
            for (int n = 0; n < 4; ++n) {
                int c = col0 + wc * 64 + n * 16 + lr;
#pragma unroll
                for (int j = 0; j < 4; ++j) {
                    int r = row0 + wr * 64 + m * 16 + 4 * lg + j;
                    C[(size_t)r * N + c] = acc[m][n][j];
                }
            }
    } else {  // EPI == 2: K_all / Vt scatter
        u16* Kall = (u16*)out0;
        u16* Vt   = (u16*)out1;
#pragma unroll
        for (int m = 0; m < 4; ++m) {
            int r0 = row0 + wr * 64 + m * 16 + 4 * lg;
            int b  = r0 >> 11;
            int s0 = r0 & (SEQ - 1);
#pragma unroll
            for (int n = 0; n < 4; ++n) {
                int c = col0 + wc * 64 + n * 16 + lr;
                int h = (unsigned)c / 192u;
                int cr = c - h * 192;
                int bh = b * NHEAD + h;
                if (cr < 64) {
#pragma unroll
                    for (int j = 0; j < 4; ++j) {
                        int s = s0 + j;
                        Kall[((size_t)bh * SEQ + s) * 128 + (cr ^ ((s & 7) << 3))] = f2bf(acc[m][n][j]);
                    }
                } else {
                    int d = cr - 64;
                    union { u16 u[4]; uint2 v; } pk;
#pragma unroll
                    for (int j = 0; j < 4; ++j) pk.u[j] = f2bf(acc[m][n][j]);
                    size_t base = ((size_t)bh * 128 + d) * SEQ + (s0 & ~63);
                    *(uint2*)&Vt[base + ((s0 & 63) ^ ((d & 7) << 3))] = pk.v;
                }
            }
        }
    }
}

// -------- RMS norm + fused k_pe build: one block per (b,s) row --------------
__global__ __launch_bounds__(256) void rmsnorm_bf(const float* __restrict__ kv,
                                                  const float* __restrict__ w,
                                                  u16* __restrict__ c_norm,
                                                  const float* __restrict__ tab,
                                                  u16* __restrict__ K_all) {
    __shared__ float red[256];
    const int row = blockIdx.x, t = threadIdx.x;
    const float* src = kv + (size_t)row * KV_W;
    float v0 = src[t], v1 = src[t + 256];
    red[t] = v0 * v0 + v1 * v1;
    __syncthreads();
    for (int s = 128; s > 0; s >>= 1) {
        if (t < s) red[t] += red[t + s];
        __syncthreads();
    }
    const float inv = rsqrtf(red[0] / (float)KV_RANK + EPS_F);
    u16* dst = c_norm + (size_t)row * KV_RANK;
    dst[t]       = f2bf(v0 * inv * w[t]);
    dst[t + 256] = f2bf(v1 * inv * w[t + 256]);

    if (t < 16) {  // fused k_pe: rope kv[512..575] -> 16 head slices
        const int dq = t;
        const int s = row & (SEQ - 1);
        const int b = row >> 11;
        float4 v = *(const float4*)(src + KV_RANK + 4 * dq);
        const int i0 = 2 * dq;
        float2 cs0 = ((const float2*)tab)[s * 32 + i0];
        float2 cs1 = ((const float2*)tab)[s * 32 + i0 + 1];
        union { u16 u[4]; uint2 w2; } pk;
        pk.u[0] = f2bf(v.x * cs0.x - v.y * cs0.y);
        pk.u[1] = f2bf(v.y * cs0.x + v.x * cs0.y);
        pk.u[2] = f2bf(v.z * cs1.x - v.w * cs1.y);
        pk.u[3] = f2bf(v.w * cs1.x + v.z * cs1.y);
        const int idx = (64 + 4 * dq) ^ ((s & 7) << 3);
#pragma unroll
        for (int h = 0; h < NHEAD; ++h) {
            int bh = b * NHEAD + h;
            *(uint2*)&K_all[((size_t)bh * SEQ + s) * 128 + idx] = pk.w2;
        }
    }
}

// ---------------- flash attention: pair-balanced blocks (R13 version) -------
#define QTILE 64
#define KTILE 64

__global__ __launch_bounds__(256, 2) void attn_mfma(const u16* __restrict__ q_bf,
                                                    const u16* __restrict__ K_all,
                                                    const u16* __restrict__ Vt,
                                                    u16* __restrict__ attn_bf) {
    __shared__ u16 Kbuf[2][KTILE * 128];   // 2 x 16KB
    __shared__ u16 Vbuf[2][128 * KTILE];   // 2 x 16KB
    __shared__ u16 Plds[4][16 * KTILE];    // 8KB, wave-private

    const int idx = blockIdx.x;                       // 0..511
    const int bh = (idx & 7) + 8 * (idx >> 7);        // 4 heads per XCD (4MB = L2)
    const int pi = (idx >> 3) & 15;                   // pair index
    const int b = bh >> 4, h = bh & 15;

    const int tid = threadIdx.x;
    const int w = tid >> 6, l = tid & 63;
    const int lr = l & 15, lg = l >> 4;
    const u16* Kb = K_all + (size_t)bh * SEQ * 128;
    const u16* Vb = Vt + (size_t)bh * 128 * SEQ;
    const int sw = (lr & 7) << 3;                     // u16-index XOR
    u16* pw = Plds[w];

    auto stage = [&](int bufi, int k0) {
        u16* kb = Kbuf[bufi];
        u16* vb = Vbuf[bufi];
#pragma unroll
        for (int it = 0; it < 4; ++it) {              // K: 1024 x 16B chunks
            int ci = it * 256 + tid;
            gload16(Kb + (((size_t)(k0 + (ci >> 4))) << 7) + ((ci & 15) << 3),
                    kb + (ci << 3));
        }
#pragma unroll
        for (int it = 0; it < 4; ++it) {              // V: 1024 x 16B chunks
            int ci = it * 256 + tid;
            gload16(Vb + (size_t)(ci >> 3) * SEQ + k0 + ((ci & 7) << 3),
                    vb + (ci << 3));
        }
    };

    const int qbA = (31 - pi) * QTILE;
    const int qbB = pi * QTILE;

    stage(0, 0);
    int cur = 0;
    for (int half = 0; half < 2; ++half) {
        const int qbase = half ? qbB : qbA;
        const int nkt = (qbase >> 6) + 1;
        const int qg = qbase + 16 * w + lr;

        const u16* qrow = q_bf + (size_t)(b * SEQ + qg) * 2048 + h * QK_HEAD;
        bf16x8 qf[4];
#pragma unroll
        for (int dc = 0; dc < 4; ++dc) qf[dc] = *(const bf16x8*)(qrow + dc * 32 + lg * 8);

        f32x4 oacc[8];
#pragma unroll
        for (int ft = 0; ft < 8; ++ft) oacc[ft] = (f32x4){0.f, 0.f, 0.f, 0.f};
        float m_r = -1e30f, l_r = 0.f;

        for (int kt = 0; kt < nkt; ++kt) {
            const int k0 = kt * KTILE;
            if (kt + 1 < nkt) {
                stage(cur ^ 1, k0 + KTILE);
                asm volatile("s_waitcnt vmcnt(8)" ::: "memory");
            } else if (half == 0) {
                stage(cur ^ 1, 0);                    // prefetch half-B tile 0
                asm volatile("s_waitcnt vmcnt(8)" ::: "memory");
            } else {
                asm volatile("s_waitcnt vmcnt(0)" ::: "memory");
            }
            __builtin_amdgcn_s_barrier();
            __builtin_amdgcn_sched_barrier(0);

            const u16* kb = Kbuf[cur];
            const u16* vb = Vbuf[cur];

            // ---- S^T = K @ Q^T ----
            f32x4 s[4];
            __builtin_amdgcn_s_setprio(1);
#pragma unroll
            for (int f = 0; f < 4; ++f) {
                s[f] = (f32x4){0.f, 0.f, 0.f, 0.f};
#pragma unroll
                for (int dc = 0; dc < 4; ++dc) {
                    bf16x8 kf = *(const bf16x8*)&kb[(16 * f + lr) * 128 + ((32 * dc + 8 * lg) ^ sw)];
                    s[f] = __builtin_amdgcn_mfma_f32_16x16x32_bf16(kf, qf[dc], s[f], 0, 0, 0);
                }
            }
            __builtin_amdgcn_s_setprio(0);

            // ---- causal mask (diagonal tile only) ----
            if (kt == nkt - 1) {
#pragma unroll
                for (int f = 0; f < 4; ++f)
#pragma unroll
                    for (int j = 0; j < 4; ++j)
                        if (k0 + 16 * f + 4 * lg + j > qg) s[f][j] = -1e30f;
            }

            // ---- online softmax (log2 domain), defer-max, asm exp2 ----
            float t0 = fmaxf(fmaxf(s[0][0], s[0][1]), fmaxf(s[0][2], s[0][3]));
            float t1 = fmaxf(fmaxf(s[1][0], s[1][1]), fmaxf(s[1][2], s[1][3]));
            float t2 = fmaxf(fmaxf(s[2][0], s[2][1]), fmaxf(s[2][2], s[2][3]));
            float t3 = fmaxf(fmaxf(s[3][0], s[3][1]), fmaxf(s[3][2], s[3][3]));
            float t = fmaxf(fmaxf(t0, t1), fmaxf(t2, t3));
            t = fmaxf(t, __shfl_xor(t, 16));
            t = fmaxf(t, __shfl_xor(t, 32));
            bool up = (t > m_r + 11.5f);              // 2^11.5 headroom
            float newm = up ? t : m_r;
            float sf_ = up ? exp2_hw(m_r - t) : 1.0f;
            m_r = newm;
            float rs = 0.f;
#pragma unroll
            for (int f = 0; f < 4; ++f)
#pragma unroll
                for (int j = 0; j < 4; ++j) {
                    float p = exp2_hw(s[f][j] - newm);
                    s[f][j] = p;
                    rs += p;
                }
            rs += __shfl_xor(rs, 16);
            rs += __shfl_xor(rs, 32);
            l_r = l_r * sf_ + rs;
            if (__any(up)) {
#pragma unroll
                for (int ft = 0; ft < 8; ++ft)
#pragma unroll
                    for (int j = 0; j < 4; ++j) oacc[ft][j] *= sf_;
            }

            // ---- P -> wave-private LDS, re-layout to B-fragment ----
#pragma unroll
            for (int f = 0; f < 4; ++f) {
                union { u16 u[4]; uint2 v; } pk;
#pragma unroll
                for (int j = 0; j < 4; ++j) pk.u[j] = f2bf(s[f][j]);
                *(uint2*)&pw[lr * 64 + ((16 * f + 4 * lg) ^ sw)] = pk.v;
            }
            asm volatile("s_waitcnt lgkmcnt(0)" ::: "memory");
            bf16x8 pfr[2];
#pragma unroll
            for (int ks = 0; ks < 2; ++ks)
                pfr[ks] = *(const bf16x8*)&pw[lr * 64 + ((32 * ks + 8 * lg) ^ sw)];

            // ---- O^T += V^T @ P^T ----
            __builtin_amdgcn_s_setprio(1);
#pragma unroll
            for (int ft = 0; ft < 8; ++ft) {
                int d = 16 * ft + lr;
#pragma unroll
                for (int ks = 0; ks < 2; ++ks) {
                    bf16x8 vf = *(const bf16x8*)&vb[d * 64 + ((32 * ks + 8 * lg) ^ sw)];
                    oacc[ft] = __builtin_amdgcn_mfma_f32_16x16x32_bf16(vf, pfr[ks], oacc[ft], 0, 0, 0);
                }
            }
            __builtin_amdgcn_s_setprio(0);

            __builtin_amdgcn_s_barrier();
            cur ^= 1;
        }

        // ---- epilogue for this half ----
        const float inv = 1.0f / l_r;
        u16* orow = attn_bf + (size_t)(b * SEQ + qg) * 2048 + h * V_HEAD;
#pragma unroll
        for (int ft = 0; ft < 8; ++ft) {
            union { u16 u[4]; uint2 v; } ok;
#pragma unroll
            for (int j = 0; j < 4; ++j) ok.u[j] = f2bf(oacc[ft][j] * inv);
            *(uint2*)(orow + 16 * ft + 4 * lg) = ok.v;
        }
    }
}

// ------------------------------------------------------------------
extern "C" void kernel_launch(void* const* d_in, const int* in_sizes, int n_in,
                              void* d_out, int out_size, void* d_ws, size_t ws_size,
                              hipStream_t stream) {
    const float* x         = (const float*)d_in[0];
    const float* w_query   = (const float*)d_in[1];
    const float* wkv_a     = (const float*)d_in[2];
    const float* wkv_b     = (const float*)d_in[3];
    const float* kv_norm_w = (const float*)d_in[4];
    const float* out_proj  = (const float*)d_in[5];

    u16* x_bf     = (u16*)d_ws;                       // 8M u16 (aliased by attn_bf)
    u16* q_bf     = x_bf + (size_t)8388608;           // 8M
    u16* c_norm   = q_bf + (size_t)8388608;           // 2M
    u16* kvdec_bf = c_norm + (size_t)2097152;         // (unused)
    u16* K_all    = kvdec_bf + (size_t)12582912;      // 8.39M
    u16* Vt       = K_all + (size_t)8388608;          // 8.39M
    u16* wT       = Vt + (size_t)8388608;             // wqT(4M) + wkvaT(1.31M) contiguous
    u16* wkvaT    = wT + (size_t)4194304;
    u16* wkvbT    = wkvaT + (size_t)1310720;          // 1.57M
    u16* opT      = wkvbT + (size_t)1572864;          // 4M
    float* kv     = (float*)(opT + (size_t)4194304);  // 2.62M floats
    float* tab    = kv + (size_t)2621440;             // 131072 floats
    u16* attn_bf  = x_bf;                             // alias (x_bf dead after merged GEMM)
    float* out = (float*)d_out;

    // 128^-0.5 * log2(e): QK scale + exp->exp2 conversion folded into q
    const float qscale2 = 0.08838834764831845f * 1.4426950408889634f;

    prep<<<19456, 256, 0, stream>>>(x, x_bf, w_query, wT, wkv_a, wkvaT,
                                    wkv_b, wkvbT, out_proj, opT, tab);

    // merged q + kv GEMM: N = 2688 = 21 col tiles, fused RoPE(q) epilogue
    gemm128<0><<<672, 256, 0, stream>>>(x_bf, wT, q_bf, kv, tab,
                                        21, 2688, 2048, qscale2);
    rmsnorm_bf<<<NTOK, 256, 0, stream>>>(kv, kv_norm_w, c_norm, tab, K_all);
    // wkv_b GEMM with fused K_all/Vt scatter epilogue: 24 x 32 tiles
    gemm128<2><<<768, 256, 0, stream>>>(c_norm, wkvbT, K_all, Vt, nullptr,
                                        24, 3072, 512, 1.0f);

    attn_mfma<<<512, 256, 0, stream>>>(q_bf, K_all, Vt, attn_bf);

    // out-proj: 16 x 32 tiles
    gemm128<1><<<512, 256, 0, stream>>>(attn_bf, opT, out, nullptr, nullptr,
                                        16, 2048, 2048, 1.0f);
}

// Round 15
// 227.092 us; speedup vs baseline: 1.1145x; 1.0009x over previous
//
#include <hip/hip_runtime.h>
#include <hip/hip_bf16.h>
#include <math.h>

#define BATCH   2
#define SEQ     2048
#define D_IN    2048
#define NHEAD   16
#define QK_ROPE 64
#define QK_NOPE 64
#define QK_HEAD 128
#define V_HEAD  128
#define KV_RANK 512
#define KV_W    640          // kv row stride (576 padded to 640)
#define NTOK    (BATCH*SEQ)  // 4096
#define EPS_F   1e-6f

typedef unsigned short u16;
typedef short bf16x8 __attribute__((ext_vector_type(8)));
typedef float f32x4  __attribute__((ext_vector_type(4)));

__device__ __forceinline__ u16 f2bf(float f) {
    unsigned u = __float_as_uint(f);
    return (u16)((u + 0x7fffu + ((u >> 16) & 1u)) >> 16);
}
__device__ __forceinline__ float bf2f(u16 u) {
    return __uint_as_float(((unsigned)u) << 16);
}
__device__ __forceinline__ float exp2_hw(float x) {
    float r;
    asm volatile("v_exp_f32 %0, %1\n\ts_nop 0" : "=v"(r) : "v"(x));
    return r;
}
__device__ __forceinline__ void gload16(const void* g, void* l) {
    __builtin_amdgcn_global_load_lds((const __attribute__((address_space(1))) unsigned int*)g,
                                     (__attribute__((address_space(3))) unsigned int*)l, 16, 0, 0);
}

// ---------------- fused preamble: convert + 4 transposes + rope table -------
__device__ __forceinline__ void transpose_sec(const float* __restrict__ src,
                                              u16* __restrict__ dst,
                                              int N, int K, int bx, int by,
                                              float (*tile)[33], int tid) {
    const int tx = tid & 31, ty = tid >> 5;
    const int nb = bx * 32, kb = by * 32;
#pragma unroll
    for (int i = 0; i < 4; ++i) {
        int k = kb + ty + 8 * i, n = nb + tx;
        tile[ty + 8 * i][tx] = (n < N) ? src[(size_t)k * N + n] : 0.f;
    }
    __syncthreads();
#pragma unroll
    for (int i = 0; i < 4; ++i) {
        int n = nb + ty + 8 * i, k = kb + tx;
        dst[(size_t)n * K + k] = f2bf(tile[tx][ty + 8 * i]);
    }
}

__global__ __launch_bounds__(256) void prep(const float* __restrict__ x, u16* __restrict__ x_bf,
                                            const float* __restrict__ wq, u16* __restrict__ wqT,
                                            const float* __restrict__ wkva, u16* __restrict__ wkvaT,
                                            const float* __restrict__ wkvb, u16* __restrict__ wkvbT,
                                            const float* __restrict__ op, u16* __restrict__ opT,
                                            float* __restrict__ tab) {
    __shared__ float tile[32][33];
    const int idx = blockIdx.x;
    const int tid = threadIdx.x;
    if (idx < 8192) {                      // x fp32 -> bf16, 4/thread
        int gid = idx * 256 + tid;
        float4 v = ((const float4*)x)[gid];
        unsigned lo = (unsigned)f2bf(v.x) | ((unsigned)f2bf(v.y) << 16);
        unsigned hi = (unsigned)f2bf(v.z) | ((unsigned)f2bf(v.w) << 16);
        ((uint2*)x_bf)[gid] = make_uint2(lo, hi);
    } else if (idx < 12288) {              // w_query^T
        int s = idx - 8192;
        transpose_sec(wq, wqT, 2048, 2048, s % 64, s / 64, tile, tid);
    } else if (idx < 13568) {              // wkv_a^T (576 -> pad 640)
        int s = idx - 12288;
        transpose_sec(wkva, wkvaT, 576, 2048, s % 20, s / 20, tile, tid);
    } else if (idx < 15104) {              // wkv_b^T
        int s = idx - 13568;
        transpose_sec(wkvb, wkvbT, 3072, 512, s % 96, s / 96, tile, tid);
    } else if (idx < 19200) {              // out_proj^T
        int s = idx - 15104;
        transpose_sec(op, opT, 2048, 2048, s % 64, s / 64, tile, tid);
    } else {                               // rope cos/sin table
        int gid = (idx - 19200) * 256 + tid;  // < SEQ*32
        int i = gid & 31, s = gid >> 5;
        float freq = __expf(-(float)(2 * i) / 64.0f * 9.210340371976184f);
        float ang = (float)s * freq;
        tab[2 * gid]     = cosf(ang);
        tab[2 * gid + 1] = sinf(ang);
    }
}

// ============ 128x128 bf16 GEMM, BK=32, 3-buf 2-tile-deep, 3 blocks/CU ======
// 256 thr = 4 waves (2M x 2N), per-wave 64x64, acc[4][4]. Counted vmcnt(4)
// tile-top + single raw s_barrier; compiler interleaves ds_read->MFMA.
// LDS PACKED AS 128-BYTE ROWS: LDS row R = global_row/2, byte col =
// (grow&1)*64 + k*2, swizzled ^((R&7)<<4) -> a 16-lane fragment sweep hits
// each 16B slot exactly twice (2-way = free, m136). Linear gload16 writes +
// inverse-swizzled GLOBAL source (rule #21 both-sides).
template <int EPI>
__global__ __launch_bounds__(256, 3) void gemm128(const u16* __restrict__ A,
                                                  const u16* __restrict__ BT,
                                                  void* __restrict__ out0,
                                                  void* __restrict__ out1,
                                                  const float* __restrict__ tab,
                                                  int gx, int N, int K, float oscale) {
    __shared__ u16 lds[24576];  // 48KB: A 3x8KB @0, B 3x8KB @12288 (u16 idx)
    const int tid = threadIdx.x;
    const int w = tid >> 6, l = tid & 63;
    const int lr = l & 15, lg = l >> 4;
    const int wr = w >> 1, wc = w & 1;
    const int nwg = gridDim.x, q8 = nwg >> 3;
    const int wg = (blockIdx.x & 7) * q8 + (blockIdx.x >> 3);
    const int row0 = (wg / gx) * 128, col0 = (wg % gx) * 128;
    const int NT = K >> 5;

    f32x4 acc[4][4];
#pragma unroll
    for (int m = 0; m < 4; ++m)
#pragma unroll
        for (int n = 0; n < 4; ++n) acc[m][n] = (f32x4){0.f, 0.f, 0.f, 0.f};

    // stage 128x32 k-tile (8KB = 64 LDS rows x 128B), 2 gloads/thread
    auto stageA = [&](int bufi, int kt) {
        u16* base = lds + bufi * 4096;
        const u16* g = A + (size_t)row0 * K + kt * 32;
#pragma unroll
        for (int i = 0; i < 2; ++i) {
            int L = (i * 256 + tid) * 16;                 // linear LDS byte
            int R = L >> 7;
            int c = ((((L >> 4) & 7) ^ (R & 7)) << 4);    // unswizzled byte col
            gload16(g + (size_t)(2 * R + (c >> 6)) * K + ((c & 63) >> 1), base + (L >> 1));
        }
    };
    auto stageB = [&](int bufi, int kt) {
        u16* base = lds + 12288 + bufi * 4096;
        const u16* g = BT + (size_t)col0 * K + kt * 32;
#pragma unroll
        for (int i = 0; i < 2; ++i) {
            int L = (i * 256 + tid) * 16;
            int R = L >> 7;
            int c = ((((L >> 4) & 7) ^ (R & 7)) << 4);
            gload16(g + (size_t)(2 * R + (c >> 6)) * K + ((c & 63) >> 1), base + (L >> 1));
        }
    };

    // prologue: tiles 0 and 1 (4 loads each, oldest-first)
    stageA(0, 0); stageB(0, 0); stageA(1, 1); stageB(1, 1);

    for (int t = 0; t < NT; ++t) {
        const int buf = t % 3, nb2 = (t + 2) % 3;
        u16* Ab = lds + buf * 4096;
        u16* Bb = lds + 12288 + buf * 4096;
        if (t + 1 < NT) asm volatile("s_waitcnt vmcnt(4)" ::: "memory");
        else            asm volatile("s_waitcnt vmcnt(0)" ::: "memory");
        __builtin_amdgcn_s_barrier();
        asm volatile("" ::: "memory");   // no LDS op may float above the barrier

        bf16x8 af[4], bfg[4];
#pragma unroll
        for (int n = 0; n < 4; ++n) {
            int grow = wc * 64 + n * 16 + lr;
            int R = grow >> 1;
            int c = ((grow & 1) << 6) + (lg << 4);
            bfg[n] = *(const bf16x8*)&Bb[(R * 128 + (c ^ ((R & 7) << 4))) >> 1];
        }
#pragma unroll
        for (int i = 0; i < 4; ++i) {
            int grow = wr * 64 + i * 16 + lr;
            int R = grow >> 1;
            int c = ((grow & 1) << 6) + (lg << 4);
            af[i] = *(const bf16x8*)&Ab[(R * 128 + (c ^ ((R & 7) << 4))) >> 1];
        }
        if (t + 2 < NT) { stageA(nb2, t + 2); stageB(nb2, t + 2); }
#pragma unroll
        for (int i = 0; i < 4; ++i)
#pragma unroll
            for (int n = 0; n < 4; ++n)
                acc[i][n] = __builtin_amdgcn_mfma_f32_16x16x32_bf16(af[i], bfg[n], acc[i][n], 0, 0, 0);
    }

    // ---- epilogues: row = row0+wr*64+m*16+4lg+j, col = col0+wc*64+n*16+lr --
    if (EPI == 0) {
        u16* qp = (u16*)out0;
        float* kvp = (float*)out1;
        const bool pe = (wc == 1);  // head-offset >= 64 -> rope half
#pragma unroll
        for (int m = 0; m < 4; ++m)
#pragma unroll
            for (int n = 0; n < 4; ++n) {
                int c = col0 + wc * 64 + n * 16 + lr;
#pragma unroll
                for (int j = 0; j < 4; ++j) {
                    int r = row0 + wr * 64 + m * 16 + 4 * lg + j;
                    float v = acc[m][n][j];
                    if (c < 2048) {
                        v *= oscale;
                        if (pe) {
                            int s = r & (SEQ - 1);
                            int ip = (16 * n + lr) >> 1;
                            float2 cs = ((const float2*)tab)[s * 32 + ip];
                            float part = __shfl_xor(v, 1);
                            v = (lr & 1) ? (v * cs.x + part * cs.y)
                                         : (v * cs.x - part * cs.y);
                        }
                        qp[(size_t)r * 2048 + c] = f2bf(v);
                    } else {
                        kvp[(size_t)r * KV_W + (c - 2048)] = v;
                    }
                }
            }
    } else if (EPI == 1) {
        float* C = (float*)out0;
#pragma unroll
        for (int m = 0; m < 4; ++m)
#pragma unroll
            for (int n = 0; n < 4; ++n) {
                int c = col0 + wc * 64 + n * 16 + lr;
#pragma unroll
                for (int j = 0; j < 4; ++j) {
                    int r = row0 + wr * 64 + m * 16 + 4 * lg + j;
                    C[(size_t)r * N + c] = acc[m][n][j];
                }
            }
    } else {  // EPI == 2: K_all / Vt scatter
        u16* Kall = (u16*)out0;
        u16* Vt   = (u16*)out1;
#pragma unroll
        for (int m = 0; m < 4; ++m) {
            int r0 = row0 + wr * 64 + m * 16 + 4 * lg;
            int b  = r0 >> 11;
            int s0 = r0 & (SEQ - 1);
#pragma unroll
            for (int n = 0; n < 4; ++n) {
                int c = col0 + wc * 64 + n * 16 + lr;
                int h = (unsigned)c / 192u;
                int cr = c - h * 192;
                int bh = b * NHEAD + h;
                if (cr < 64) {
#pragma unroll
                    for (int j = 0; j < 4; ++j) {
                        int s = s0 + j;
                        Kall[((size_t)bh * SEQ + s) * 128 + (cr ^ ((s & 7) << 3))] = f2bf(acc[m][n][j]);
                    }
                } else {
                    int d = cr - 64;
                    union { u16 u[4]; uint2 v; } pk;
#pragma unroll
                    for (int j = 0; j < 4; ++j) pk.u[j] = f2bf(acc[m][n][j]);
                    size_t base = ((size_t)bh * 128 + d) * SEQ + (s0 & ~63);
                    *(uint2*)&Vt[base + ((s0 & 63) ^ ((d & 7) << 3))] = pk.v;
                }
            }
        }
    }
}

// -------- RMS norm + fused k_pe build: one block per (b,s) row --------------
__global__ __launch_bounds__(256) void rmsnorm_bf(const float* __restrict__ kv,
                                                  const float* __restrict__ w,
                                                  u16* __restrict__ c_norm,
                                                  const float* __restrict__ tab,
                                                  u16* __restrict__ K_all) {
    __shared__ float red[256];
    const int row = blockIdx.x, t = threadIdx.x;
    const float* src = kv + (size_t)row * KV_W;
    float v0 = src[t], v1 = src[t + 256];
    red[t] = v0 * v0 + v1 * v1;
    __syncthreads();
    for (int s = 128; s > 0; s >>= 1) {
        if (t < s) red[t] += red[t + s];
        __syncthreads();
    }
    const float inv = rsqrtf(red[0] / (float)KV_RANK + EPS_F);
    u16* dst = c_norm + (size_t)row * KV_RANK;
    dst[t]       = f2bf(v0 * inv * w[t]);
    dst[t + 256] = f2bf(v1 * inv * w[t + 256]);

    if (t < 16) {  // fused k_pe: rope kv[512..575] -> 16 head slices
        const int dq = t;
        const int s = row & (SEQ - 1);
        const int b = row >> 11;
        float4 v = *(const float4*)(src + KV_RANK + 4 * dq);
        const int i0 = 2 * dq;
        float2 cs0 = ((const float2*)tab)[s * 32 + i0];
        float2 cs1 = ((const float2*)tab)[s * 32 + i0 + 1];
        union { u16 u[4]; uint2 w2; } pk;
        pk.u[0] = f2bf(v.x * cs0.x - v.y * cs0.y);
        pk.u[1] = f2bf(v.y * cs0.x + v.x * cs0.y);
        pk.u[2] = f2bf(v.z * cs1.x - v.w * cs1.y);
        pk.u[3] = f2bf(v.w * cs1.x + v.z * cs1.y);
        const int idx = (64 + 4 * dq) ^ ((s & 7) << 3);
#pragma unroll
        for (int h = 0; h < NHEAD; ++h) {
            int bh = b * NHEAD + h;
            *(uint2*)&K_all[((size_t)bh * SEQ + s) * 128 + idx] = pk.w2;
        }
    }
}

// ---------------- flash attention: pair-balanced blocks ---------------------
#define QTILE 64
#define KTILE 64

__global__ __launch_bounds__(256, 2) void attn_mfma(const u16* __restrict__ q_bf,
                                                    const u16* __restrict__ K_all,
                                                    const u16* __restrict__ Vt,
                                                    u16* __restrict__ attn_bf) {
    __shared__ u16 Kbuf[2][KTILE * 128];   // 2 x 16KB
    __shared__ u16 Vbuf[2][128 * KTILE];   // 2 x 16KB
    __shared__ u16 Plds[4][16 * KTILE];    // 8KB, wave-private

    const int idx = blockIdx.x;                       // 0..511
    const int bh = (idx & 7) + 8 * (idx >> 7);        // 4 heads per XCD (4MB = L2)
    const int pi = (idx >> 3) & 15;                   // pair index
    const int b = bh >> 4, h = bh & 15;

    const int tid = threadIdx.x;
    const int w = tid >> 6, l = tid & 63;
    const int lr = l & 15, lg = l >> 4;
    const u16* Kb = K_all + (size_t)bh * SEQ * 128;
    const u16* Vb = Vt + (size_t)bh * 128 * SEQ;
    const int sw = (lr & 7) << 3;                     // u16-index XOR
    u16* pw = Plds[w];

    auto stage = [&](int bufi, int k0) {
        u16* kb = Kbuf[bufi];
        u16* vb = Vbuf[bufi];
#pragma unroll
        for (int it = 0; it < 4; ++it) {              // K: 1024 x 16B chunks
            int ci = it * 256 + tid;
            gload16(Kb + (((size_t)(k0 + (ci >> 4))) << 7) + ((ci & 15) << 3),
                    kb + (ci << 3));
        }
#pragma unroll
        for (int it = 0; it < 4; ++it) {              // V: 1024 x 16B chunks
            int ci = it * 256 + tid;
            gload16(Vb + (size_t)(ci >> 3) * SEQ + k0 + ((ci & 7) << 3),
                    vb + (ci << 3));
        }
    };

    const int qbA = (31 - pi) * QTILE;
    const int qbB = pi * QTILE;

    stage(0, 0);
    int cur = 0;
    for (int half = 0; half < 2; ++half) {
        const int qbase = half ? qbB : qbA;
        const int nkt = (qbase >> 6) + 1;
        const int qg = qbase + 16 * w + lr;

        const u16* qrow = q_bf + (size_t)(b * SEQ + qg) * 2048 + h * QK_HEAD;
        bf16x8 qf[4];
#pragma unroll
        for (int dc = 0; dc < 4; ++dc) qf[dc] = *(const bf16x8*)(qrow + dc * 32 + lg * 8);

        f32x4 oacc[8];
#pragma unroll
        for (int ft = 0; ft < 8; ++ft) oacc[ft] = (f32x4){0.f, 0.f, 0.f, 0.f};
        float m_r = -1e30f, l_r = 0.f;

        for (int kt = 0; kt < nkt; ++kt) {
            const int k0 = kt * KTILE;
            if (kt + 1 < nkt) {
                stage(cur ^ 1, k0 + KTILE);
                asm volatile("s_waitcnt vmcnt(8)" ::: "memory");
            } else if (half == 0) {
                stage(cur ^ 1, 0);                    // prefetch half-B tile 0
                asm volatile("s_waitcnt vmcnt(8)" ::: "memory");
            } else {
                asm volatile("s_waitcnt vmcnt(0)" ::: "memory");
            }
            __builtin_amdgcn_s_barrier();
            __builtin_amdgcn_sched_barrier(0);

            const u16* kb = Kbuf[cur];
            const u16* vb = Vbuf[cur];

            // ---- S^T = K @ Q^T ----
            f32x4 s[4];
            __builtin_amdgcn_s_setprio(1);
#pragma unroll
            for (int f = 0; f < 4; ++f) {
                s[f] = (f32x4){0.f, 0.f, 0.f, 0.f};
#pragma unroll
                for (int dc = 0; dc < 4; ++dc) {
                    bf16x8 kf = *(const bf16x8*)&kb[(16 * f + lr) * 128 + ((32 * dc + 8 * lg) ^ sw)];
                    s[f] = __builtin_amdgcn_mfma_f32_16x16x32_bf16(kf, qf[dc], s[f], 0, 0, 0);
                }
            }
            __builtin_amdgcn_s_setprio(0);

            // ---- causal mask (diagonal tile only) ----
            if (kt == nkt - 1) {
#pragma unroll
                for (int f = 0; f < 4; ++f)
#pragma unroll
                    for (int j = 0; j < 4; ++j)
                        if (k0 + 16 * f + 4 * lg + j > qg) s[f][j] = -1e30f;
            }

            // ---- online softmax (log2 domain), defer-max, asm exp2 ----
            float t0 = fmaxf(fmaxf(s[0][0], s[0][1]), fmaxf(s[0][2], s[0][3]));
            float t1 = fmaxf(fmaxf(s[1][0], s[1][1]), fmaxf(s[1][2], s[1][3]));
            float t2 = fmaxf(fmaxf(s[2][0], s[2][1]), fmaxf(s[2][2], s[2][3]));
            float t3 = fmaxf(fmaxf(s[3][0], s[3][1]), fmaxf(s[3][2], s[3][3]));
            float t = fmaxf(fmaxf(t0, t1), fmaxf(t2, t3));
            t = fmaxf(t, __shfl_xor(t, 16));
            t = fmaxf(t, __shfl_xor(t, 32));
            bool up = (t > m_r + 11.5f);              // 2^11.5 headroom
            float newm = up ? t : m_r;
            float sf_ = up ? exp2_hw(m_r - t) : 1.0f;
            m_r = newm;
            float rs = 0.f;
#pragma unroll
            for (int f = 0; f < 4; ++f)
#pragma unroll
                for (int j = 0; j < 4; ++j) {
                    float p = exp2_hw(s[f][j] - newm);
                    s[f][j] = p;
                    rs += p;
                }
            rs += __shfl_xor(rs, 16);
            rs += __shfl_xor(rs, 32);
            l_r = l_r * sf_ + rs;
            if (__any(up)) {
#pragma unroll
                for (int ft = 0; ft < 8; ++ft)
#pragma unroll
                    for (int j = 0; j < 4; ++j) oacc[ft][j] *= sf_;
            }

            // ---- P -> wave-private LDS, re-layout to B-fragment ----
#pragma unroll
            for (int f = 0; f < 4; ++f) {
                union { u16 u[4]; uint2 v; } pk;
#pragma unroll
                for (int j = 0; j < 4; ++j) pk.u[j] = f2bf(s[f][j]);
                *(uint2*)&pw[lr * 64 + ((16 * f + 4 * lg) ^ sw)] = pk.v;
            }
            asm volatile("s_waitcnt lgkmcnt(0)" ::: "memory");
            bf16x8 pfr[2];
#pragma unroll
            for (int ks = 0; ks < 2; ++ks)
                pfr[ks] = *(const bf16x8*)&pw[lr * 64 + ((32 * ks + 8 * lg) ^ sw)];

            // ---- O^T += V^T @ P^T ----
            __builtin_amdgcn_s_setprio(1);
#pragma unroll
            for (int ft = 0; ft < 8; ++ft) {
                int d = 16 * ft + lr;
#pragma unroll
                for (int ks = 0; ks < 2; ++ks) {
                    bf16x8 vf = *(const bf16x8*)&vb[d * 64 + ((32 * ks + 8 * lg) ^ sw)];
                    oacc[ft] = __builtin_amdgcn_mfma_f32_16x16x32_bf16(vf, pfr[ks], oacc[ft], 0, 0, 0);
                }
            }
            __builtin_amdgcn_s_setprio(0);

            __builtin_amdgcn_s_barrier();
            cur ^= 1;
        }

        // ---- epilogue for this half ----
        const float inv = 1.0f / l_r;
        u16* orow = attn_bf + (size_t)(b * SEQ + qg) * 2048 + h * V_HEAD;
#pragma unroll
        for (int ft = 0; ft < 8; ++ft) {
            union { u16 u[4]; uint2 v; } ok;
#pragma unroll
            for (int j = 0; j < 4; ++j) ok.u[j] = f2bf(oacc[ft][j] * inv);
            *(uint2*)(orow + 16 * ft + 4 * lg) = ok.v;
        }
    }
}

// ------------------------------------------------------------------
extern "C" void kernel_launch(void* const* d_in, const int* in_sizes, int n_in,
                              void* d_out, int out_size, void* d_ws, size_t ws_size,
                              hipStream_t stream) {
    const float* x         = (const float*)d_in[0];
    const float* w_query   = (const float*)d_in[1];
    const float* wkv_a     = (const float*)d_in[2];
    const float* wkv_b     = (const float*)d_in[3];
    const float* kv_norm_w = (const float*)d_in[4];
    const float* out_proj  = (const float*)d_in[5];

    u16* x_bf     = (u16*)d_ws;                       // 8M u16 (aliased by attn_bf)
    u16* q_bf     = x_bf + (size_t)8388608;           // 8M
    u16* c_norm   = q_bf + (size_t)8388608;           // 2M
    u16* kvdec_bf = c_norm + (size_t)2097152;         // (unused)
    u16* K_all    = kvdec_bf + (size_t)12582912;      // 8.39M
    u16* Vt       = K_all + (size_t)8388608;          // 8.39M
    u16* wT       = Vt + (size_t)8388608;             // wqT(4M) + wkvaT(1.31M) contiguous
    u16* wkvaT    = wT + (size_t)4194304;
    u16* wkvbT    = wkvaT + (size_t)1310720;          // 1.57M
    u16* opT      = wkvbT + (size_t)1572864;          // 4M
    float* kv     = (float*)(opT + (size_t)4194304);  // 2.62M floats
    float* tab    = kv + (size_t)2621440;             // 131072 floats
    u16* attn_bf  = x_bf;                             // alias (x_bf dead after merged GEMM)
    float* out = (float*)d_out;

    // 128^-0.5 * log2(e): QK scale + exp->exp2 conversion folded into q
    const float qscale2 = 0.08838834764831845f * 1.4426950408889634f;

    prep<<<19456, 256, 0, stream>>>(x, x_bf, w_query, wT, wkv_a, wkvaT,
                                    wkv_b, wkvbT, out_proj, opT, tab);

    // merged q + kv GEMM: N = 2688 = 21 col tiles, fused RoPE(q) epilogue
    gemm128<0><<<672, 256, 0, stream>>>(x_bf, wT, q_bf, kv, tab,
                                        21, 2688, 2048, qscale2);
    rmsnorm_bf<<<NTOK, 256, 0, stream>>>(kv, kv_norm_w, c_norm, tab, K_all);
    // wkv_b GEMM with fused K_all/Vt scatter epilogue: 24 x 32 tiles
    gemm128<2><<<768, 256, 0, stream>>>(c_norm, wkvbT, K_all, Vt, nullptr,
                                        24, 3072, 512, 1.0f);

    attn_mfma<<<512, 256, 0, stream>>>(q_bf, K_all, Vt, attn_bf);

    // out-proj: 16 x 32 tiles
    gemm128<1><<<512, 256, 0, stream>>>(attn_bf, opT, out, nullptr, nullptr,
                                        16, 2048, 2048, 1.0f);
}

// Round 16
// 223.335 us; speedup vs baseline: 1.1332x; 1.0168x over previous
//
#include <hip/hip_runtime.h>
#include <hip/hip_bf16.h>
#include <math.h>

#define BATCH   2
#define SEQ     2048
#define D_IN    2048
#define NHEAD   16
#define QK_ROPE 64
#define QK_NOPE 64
#define QK_HEAD 128
#define V_HEAD  128
#define KV_RANK 512
#define KV_W    640          // kv row stride (576 padded to 640)
#define NTOK    (BATCH*SEQ)  // 4096
#define EPS_F   1e-6f

typedef unsigned short u16;
typedef short bf16x8 __attribute__((ext_vector_type(8)));
typedef float f32x4  __attribute__((ext_vector_type(4)));

__device__ __forceinline__ u16 f2bf(float f) {
    unsigned u = __float_as_uint(f);
    return (u16)((u + 0x7fffu + ((u >> 16) & 1u)) >> 16);
}
__device__ __forceinline__ float bf2f(u16 u) {
    return __uint_as_float(((unsigned)u) << 16);
}
__device__ __forceinline__ float exp2_hw(float x) {
    float r;
    asm volatile("v_exp_f32 %0, %1\n\ts_nop 0" : "=v"(r) : "v"(x));
    return r;
}
__device__ __forceinline__ void gload16(const void* g, void* l) {
    __builtin_amdgcn_global_load_lds((const __attribute__((address_space(1))) unsigned int*)g,
                                     (__attribute__((address_space(3))) unsigned int*)l, 16, 0, 0);
}

// ---------------- fused preamble: convert + 4 transposes + rope table -------
__device__ __forceinline__ void transpose_sec(const float* __restrict__ src,
                                              u16* __restrict__ dst,
                                              int N, int K, int bx, int by,
                                              float (*tile)[33], int tid) {
    const int tx = tid & 31, ty = tid >> 5;
    const int nb = bx * 32, kb = by * 32;
#pragma unroll
    for (int i = 0; i < 4; ++i) {
        int k = kb + ty + 8 * i, n = nb + tx;
        tile[ty + 8 * i][tx] = (n < N) ? src[(size_t)k * N + n] : 0.f;
    }
    __syncthreads();
#pragma unroll
    for (int i = 0; i < 4; ++i) {
        int n = nb + ty + 8 * i, k = kb + tx;
        dst[(size_t)n * K + k] = f2bf(tile[tx][ty + 8 * i]);
    }
}

__global__ __launch_bounds__(256) void prep(const float* __restrict__ x, u16* __restrict__ x_bf,
                                            const float* __restrict__ wq, u16* __restrict__ wqT,
                                            const float* __restrict__ wkva, u16* __restrict__ wkvaT,
                                            const float* __restrict__ wkvb, u16* __restrict__ wkvbT,
                                            const float* __restrict__ op, u16* __restrict__ opT,
                                            float* __restrict__ tab) {
    __shared__ float tile[32][33];
    const int idx = blockIdx.x;
    const int tid = threadIdx.x;
    if (idx < 8192) {                      // x fp32 -> bf16, 4/thread
        int gid = idx * 256 + tid;
        float4 v = ((const float4*)x)[gid];
        unsigned lo = (unsigned)f2bf(v.x) | ((unsigned)f2bf(v.y) << 16);
        unsigned hi = (unsigned)f2bf(v.z) | ((unsigned)f2bf(v.w) << 16);
        ((uint2*)x_bf)[gid] = make_uint2(lo, hi);
    } else if (idx < 12288) {              // w_query^T
        int s = idx - 8192;
        transpose_sec(wq, wqT, 2048, 2048, s % 64, s / 64, tile, tid);
    } else if (idx < 13568) {              // wkv_a^T (576 -> pad 640)
        int s = idx - 12288;
        transpose_sec(wkva, wkvaT, 576, 2048, s % 20, s / 20, tile, tid);
    } else if (idx < 15104) {              // wkv_b^T
        int s = idx - 13568;
        transpose_sec(wkvb, wkvbT, 3072, 512, s % 96, s / 96, tile, tid);
    } else if (idx < 19200) {              // out_proj^T
        int s = idx - 15104;
        transpose_sec(op, opT, 2048, 2048, s % 64, s / 64, tile, tid);
    } else {                               // rope cos/sin table
        int gid = (idx - 19200) * 256 + tid;  // < SEQ*32
        int i = gid & 31, s = gid >> 5;
        float freq = __expf(-(float)(2 * i) / 64.0f * 9.210340371976184f);
        float ang = (float)s * freq;
        tab[2 * gid]     = cosf(ang);
        tab[2 * gid + 1] = sinf(ang);
    }
}

// ============ 128x128 bf16 GEMM, BK=32, 2-buf, ~5 blocks/CU =================
// 256 thr = 4 waves (2M x 2N), per-wave 64x64, acc[4][4]. 32KB LDS (2 bufs)
// -> up to 5 resident blocks/CU (20 waves) for cross-block latency hiding.
// Per tile: [vmcnt(0) - only tile t's 4 loads outstanding, issued 1 tile ago]
// [s_barrier][8 ds_read + stage t+1][MFMA x16]. Single barrier/tile is safe:
// all waves' reads of tile t-1 completed before they arrived at barrier(t),
// and stage(t+1) (same buffer as t-1) is issued only after passing it.
// LDS packed as 128-byte rows: row R = grow/2, col = (grow&1)*64 + k*2,
// swizzled ^((R&7)<<4); 16-lane sweep = 2-way bank access (free, m136).
// Linear gload16 writes + inverse-swizzled GLOBAL source (rule #21).
template <int EPI>
__global__ __launch_bounds__(256, 4) void gemm128(const u16* __restrict__ A,
                                                  const u16* __restrict__ BT,
                                                  void* __restrict__ out0,
                                                  void* __restrict__ out1,
                                                  const float* __restrict__ tab,
                                                  int gx, int N, int K, float oscale) {
    __shared__ u16 lds[16384];  // 32KB: A 2x8KB @0, B 2x8KB @8192 (u16 idx)
    const int tid = threadIdx.x;
    const int w = tid >> 6, l = tid & 63;
    const int lr = l & 15, lg = l >> 4;
    const int wr = w >> 1, wc = w & 1;
    const int nwg = gridDim.x, q8 = nwg >> 3;
    const int wg = (blockIdx.x & 7) * q8 + (blockIdx.x >> 3);
    const int row0 = (wg / gx) * 128, col0 = (wg % gx) * 128;
    const int NT = K >> 5;

    f32x4 acc[4][4];
#pragma unroll
    for (int m = 0; m < 4; ++m)
#pragma unroll
        for (int n = 0; n < 4; ++n) acc[m][n] = (f32x4){0.f, 0.f, 0.f, 0.f};

    // stage 128x32 k-tile (8KB = 64 LDS rows x 128B), 2 gloads/thread
    auto stageA = [&](int bufi, int kt) {
        u16* base = lds + bufi * 4096;
        const u16* g = A + (size_t)row0 * K + kt * 32;
#pragma unroll
        for (int i = 0; i < 2; ++i) {
            int L = (i * 256 + tid) * 16;                 // linear LDS byte
            int R = L >> 7;
            int c = ((((L >> 4) & 7) ^ (R & 7)) << 4);    // unswizzled byte col
            gload16(g + (size_t)(2 * R + (c >> 6)) * K + ((c & 63) >> 1), base + (L >> 1));
        }
    };
    auto stageB = [&](int bufi, int kt) {
        u16* base = lds + 8192 + bufi * 4096;
        const u16* g = BT + (size_t)col0 * K + kt * 32;
#pragma unroll
        for (int i = 0; i < 2; ++i) {
            int L = (i * 256 + tid) * 16;
            int R = L >> 7;
            int c = ((((L >> 4) & 7) ^ (R & 7)) << 4);
            gload16(g + (size_t)(2 * R + (c >> 6)) * K + ((c & 63) >> 1), base + (L >> 1));
        }
    };

    // prologue: tile 0
    stageA(0, 0); stageB(0, 0);

    for (int t = 0; t < NT; ++t) {
        const int buf = t & 1;
        u16* Ab = lds + buf * 4096;
        u16* Bb = lds + 8192 + buf * 4096;
        asm volatile("s_waitcnt vmcnt(0)" ::: "memory");  // tile t landed (issued 1 tile ago)
        __builtin_amdgcn_s_barrier();
        asm volatile("" ::: "memory");   // no LDS op may float above the barrier

        bf16x8 af[4], bfg[4];
#pragma unroll
        for (int n = 0; n < 4; ++n) {
            int grow = wc * 64 + n * 16 + lr;
            int R = grow >> 1;
            int c = ((grow & 1) << 6) + (lg << 4);
            bfg[n] = *(const bf16x8*)&Bb[(R * 128 + (c ^ ((R & 7) << 4))) >> 1];
        }
#pragma unroll
        for (int i = 0; i < 4; ++i) {
            int grow = wr * 64 + i * 16 + lr;
            int R = grow >> 1;
            int c = ((grow & 1) << 6) + (lg << 4);
            af[i] = *(const bf16x8*)&Ab[(R * 128 + (c ^ ((R & 7) << 4))) >> 1];
        }
        if (t + 1 < NT) { stageA(buf ^ 1, t + 1); stageB(buf ^ 1, t + 1); }
#pragma unroll
        for (int i = 0; i < 4; ++i)
#pragma unroll
            for (int n = 0; n < 4; ++n)
                acc[i][n] = __builtin_amdgcn_mfma_f32_16x16x32_bf16(af[i], bfg[n], acc[i][n], 0, 0, 0);
    }

    // ---- epilogues: row = row0+wr*64+m*16+4lg+j, col = col0+wc*64+n*16+lr --
    if (EPI == 0) {
        u16* qp = (u16*)out0;
        float* kvp = (float*)out1;
        const bool pe = (wc == 1);  // head-offset >= 64 -> rope half
#pragma unroll
        for (int m = 0; m < 4; ++m)
#pragma unroll
            for (int n = 0; n < 4; ++n) {
                int c = col0 + wc * 64 + n * 16 + lr;
#pragma unroll
                for (int j = 0; j < 4; ++j) {
                    int r = row0 + wr * 64 + m * 16 + 4 * lg + j;
                    float v = acc[m][n][j];
                    if (c < 2048) {
                        v *= oscale;
                        if (pe) {
                            int s = r & (SEQ - 1);
                            int ip = (16 * n + lr) >> 1;
                            float2 cs = ((const float2*)tab)[s * 32 + ip];
                            float part = __shfl_xor(v, 1);
                            v = (lr & 1) ? (v * cs.x + part * cs.y)
                                         : (v * cs.x - part * cs.y);
                        }
                        qp[(size_t)r * 2048 + c] = f2bf(v);
                    } else {
                        kvp[(size_t)r * KV_W + (c - 2048)] = v;
                    }
                }
            }
    } else if (EPI == 1) {
        float* C = (float*)out0;
#pragma unroll
        for (int m = 0; m < 4; ++m)
#pragma unroll
            for (int n = 0; n < 4; ++n) {
                int c = col0 + wc * 64 + n * 16 + lr;
#pragma unroll
                for (int j = 0; j < 4; ++j) {
                    int r = row0 + wr * 64 + m * 16 + 4 * lg + j;
                    C[(size_t)r * N + c] = acc[m][n][j];
                }
            }
    } else {  // EPI == 2: K_all / Vt scatter
        u16* Kall = (u16*)out0;
        u16* Vt   = (u16*)out1;
#pragma unroll
        for (int m = 0; m < 4; ++m) {
            int r0 = row0 + wr * 64 + m * 16 + 4 * lg;
            int b  = r0 >> 11;
            int s0 = r0 & (SEQ - 1);
#pragma unroll
            for (int n = 0; n < 4; ++n) {
                int c = col0 + wc * 64 + n * 16 + lr;
                int h = (unsigned)c / 192u;
                int cr = c - h * 192;
                int bh = b * NHEAD + h;
                if (cr < 64) {
#pragma unroll
                    for (int j = 0; j < 4; ++j) {
                        int s = s0 + j;
                        Kall[((size_t)bh * SEQ + s) * 128 + (cr ^ ((s & 7) << 3))] = f2bf(acc[m][n][j]);
                    }
                } else {
                    int d = cr - 64;
                    union { u16 u[4]; uint2 v; } pk;
#pragma unroll
                    for (int j = 0; j < 4; ++j) pk.u[j] = f2bf(acc[m][n][j]);
                    size_t base = ((size_t)bh * 128 + d) * SEQ + (s0 & ~63);
                    *(uint2*)&Vt[base + ((s0 & 63) ^ ((d & 7) << 3))] = pk.v;
                }
            }
        }
    }
}

// -------- RMS norm + fused k_pe build: one block per (b,s) row --------------
__global__ __launch_bounds__(256) void rmsnorm_bf(const float* __restrict__ kv,
                                                  const float* __restrict__ w,
                                                  u16* __restrict__ c_norm,
                                                  const float* __restrict__ tab,
                                                  u16* __restrict__ K_all) {
    __shared__ float red[256];
    const int row = blockIdx.x, t = threadIdx.x;
    const float* src = kv + (size_t)row * KV_W;
    float v0 = src[t], v1 = src[t + 256];
    red[t] = v0 * v0 + v1 * v1;
    __syncthreads();
    for (int s = 128; s > 0; s >>= 1) {
        if (t < s) red[t] += red[t + s];
        __syncthreads();
    }
    const float inv = rsqrtf(red[0] / (float)KV_RANK + EPS_F);
    u16* dst = c_norm + (size_t)row * KV_RANK;
    dst[t]       = f2bf(v0 * inv * w[t]);
    dst[t + 256] = f2bf(v1 * inv * w[t + 256]);

    if (t < 16) {  // fused k_pe: rope kv[512..575] -> 16 head slices
        const int dq = t;
        const int s = row & (SEQ - 1);
        const int b = row >> 11;
        float4 v = *(const float4*)(src + KV_RANK + 4 * dq);
        const int i0 = 2 * dq;
        float2 cs0 = ((const float2*)tab)[s * 32 + i0];
        float2 cs1 = ((const float2*)tab)[s * 32 + i0 + 1];
        union { u16 u[4]; uint2 w2; } pk;
        pk.u[0] = f2bf(v.x * cs0.x - v.y * cs0.y);
        pk.u[1] = f2bf(v.y * cs0.x + v.x * cs0.y);
        pk.u[2] = f2bf(v.z * cs1.x - v.w * cs1.y);
        pk.u[3] = f2bf(v.w * cs1.x + v.z * cs1.y);
        const int idx = (64 + 4 * dq) ^ ((s & 7) << 3);
#pragma unroll
        for (int h = 0; h < NHEAD; ++h) {
            int bh = b * NHEAD + h;
            *(uint2*)&K_all[((size_t)bh * SEQ + s) * 128 + idx] = pk.w2;
        }
    }
}

// ---------------- flash attention: pair-balanced blocks ---------------------
#define QTILE 64
#define KTILE 64

__global__ __launch_bounds__(256, 2) void attn_mfma(const u16* __restrict__ q_bf,
                                                    const u16* __restrict__ K_all,
                                                    const u16* __restrict__ Vt,
                                                    u16* __restrict__ attn_bf) {
    __shared__ u16 Kbuf[2][KTILE * 128];   // 2 x 16KB
    __shared__ u16 Vbuf[2][128 * KTILE];   // 2 x 16KB
    __shared__ u16 Plds[4][16 * KTILE];    // 8KB, wave-private

    const int idx = blockIdx.x;                       // 0..511
    const int bh = (idx & 7) + 8 * (idx >> 7);        // 4 heads per XCD (4MB = L2)
    const int pi = (idx >> 3) & 15;                   // pair index
    const int b = bh >> 4, h = bh & 15;

    const int tid = threadIdx.x;
    const int w = tid >> 6, l = tid & 63;
    const int lr = l & 15, lg = l >> 4;
    const u16* Kb = K_all + (size_t)bh * SEQ * 128;
    const u16* Vb = Vt + (size_t)bh * 128 * SEQ;
    const int sw = (lr & 7) << 3;                     // u16-index XOR
    u16* pw = Plds[w];

    auto stage = [&](int bufi, int k0) {
        u16* kb = Kbuf[bufi];
        u16* vb = Vbuf[bufi];
#pragma unroll
        for (int it = 0; it < 4; ++it) {              // K: 1024 x 16B chunks
            int ci = it * 256 + tid;
            gload16(Kb + (((size_t)(k0 + (ci >> 4))) << 7) + ((ci & 15) << 3),
                    kb + (ci << 3));
        }
#pragma unroll
        for (int it = 0; it < 4; ++it) {              // V: 1024 x 16B chunks
            int ci = it * 256 + tid;
            gload16(Vb + (size_t)(ci >> 3) * SEQ + k0 + ((ci & 7) << 3),
                    vb + (ci << 3));
        }
    };

    const int qbA = (31 - pi) * QTILE;
    const int qbB = pi * QTILE;

    stage(0, 0);
    int cur = 0;
    for (int half = 0; half < 2; ++half) {
        const int qbase = half ? qbB : qbA;
        const int nkt = (qbase >> 6) + 1;
        const int qg = qbase + 16 * w + lr;

        const u16* qrow = q_bf + (size_t)(b * SEQ + qg) * 2048 + h * QK_HEAD;
        bf16x8 qf[4];
#pragma unroll
        for (int dc = 0; dc < 4; ++dc) qf[dc] = *(const bf16x8*)(qrow + dc * 32 + lg * 8);

        f32x4 oacc[8];
#pragma unroll
        for (int ft = 0; ft < 8; ++ft) oacc[ft] = (f32x4){0.f, 0.f, 0.f, 0.f};
        float m_r = -1e30f, l_r = 0.f;

        for (int kt = 0; kt < nkt; ++kt) {
            const int k0 = kt * KTILE;
            if (kt + 1 < nkt) {
                stage(cur ^ 1, k0 + KTILE);
                asm volatile("s_waitcnt vmcnt(8)" ::: "memory");
            } else if (half == 0) {
                stage(cur ^ 1, 0);                    // prefetch half-B tile 0
                asm volatile("s_waitcnt vmcnt(8)" ::: "memory");
            } else {
                asm volatile("s_waitcnt vmcnt(0)" ::: "memory");
            }
            __builtin_amdgcn_s_barrier();
            __builtin_amdgcn_sched_barrier(0);

            const u16* kb = Kbuf[cur];
            const u16* vb = Vbuf[cur];

            // ---- S^T = K @ Q^T ----
            f32x4 s[4];
            __builtin_amdgcn_s_setprio(1);
#pragma unroll
            for (int f = 0; f < 4; ++f) {
                s[f] = (f32x4){0.f, 0.f, 0.f, 0.f};
#pragma unroll
                for (int dc = 0; dc < 4; ++dc) {
                    bf16x8 kf = *(const bf16x8*)&kb[(16 * f + lr) * 128 + ((32 * dc + 8 * lg) ^ sw)];
                    s[f] = __builtin_amdgcn_mfma_f32_16x16x32_bf16(kf, qf[dc], s[f], 0, 0, 0);
                }
            }
            __builtin_amdgcn_s_setprio(0);

            // ---- causal mask (diagonal tile only) ----
            if (kt == nkt - 1) {
#pragma unroll
                for (int f = 0; f < 4; ++f)
#pragma unroll
                    for (int j = 0; j < 4; ++j)
                        if (k0 + 16 * f + 4 * lg + j > qg) s[f][j] = -1e30f;
            }

            // ---- online softmax (log2 domain), defer-max, asm exp2 ----
            float t0 = fmaxf(fmaxf(s[0][0], s[0][1]), fmaxf(s[0][2], s[0][3]));
            float t1 = fmaxf(fmaxf(s[1][0], s[1][1]), fmaxf(s[1][2], s[1][3]));
            float t2 = fmaxf(fmaxf(s[2][0], s[2][1]), fmaxf(s[2][2], s[2][3]));
            float t3 = fmaxf(fmaxf(s[3][0], s[3][1]), fmaxf(s[3][2], s[3][3]));
            float t = fmaxf(fmaxf(t0, t1), fmaxf(t2, t3));
            t = fmaxf(t, __shfl_xor(t, 16));
            t = fmaxf(t, __shfl_xor(t, 32));
            bool up = (t > m_r + 11.5f);              // 2^11.5 headroom
            float newm = up ? t : m_r;
            float sf_ = up ? exp2_hw(m_r - t) : 1.0f;
            m_r = newm;
            float rs = 0.f;
#pragma unroll
            for (int f = 0; f < 4; ++f)
#pragma unroll
                for (int j = 0; j < 4; ++j) {
                    float p = exp2_hw(s[f][j] - newm);
                    s[f][j] = p;
                    rs += p;
                }
            rs += __shfl_xor(rs, 16);
            rs += __shfl_xor(rs, 32);
            l_r = l_r * sf_ + rs;
            if (__any(up)) {
#pragma unroll
                for (int ft = 0; ft < 8; ++ft)
#pragma unroll
                    for (int j = 0; j < 4; ++j) oacc[ft][j] *= sf_;
            }

            // ---- P -> wave-private LDS, re-layout to B-fragment ----
#pragma unroll
            for (int f = 0; f < 4; ++f) {
                union { u16 u[4]; uint2 v; } pk;
#pragma unroll
                for (int j = 0; j < 4; ++j) pk.u[j] = f2bf(s[f][j]);
                *(uint2*)&pw[lr * 64 + ((16 * f + 4 * lg) ^ sw)] = pk.v;
            }
            asm volatile("s_waitcnt lgkmcnt(0)" ::: "memory");
            bf16x8 pfr[2];
#pragma unroll
            for (int ks = 0; ks < 2; ++ks)
                pfr[ks] = *(const bf16x8*)&pw[lr * 64 + ((32 * ks + 8 * lg) ^ sw)];

            // ---- O^T += V^T @ P^T ----
            __builtin_amdgcn_s_setprio(1);
#pragma unroll
            for (int ft = 0; ft < 8; ++ft) {
                int d = 16 * ft + lr;
#pragma unroll
                for (int ks = 0; ks < 2; ++ks) {
                    bf16x8 vf = *(const bf16x8*)&vb[d * 64 + ((32 * ks + 8 * lg) ^ sw)];
                    oacc[ft] = __builtin_amdgcn_mfma_f32_16x16x32_bf16(vf, pfr[ks], oacc[ft], 0, 0, 0);
                }
            }
            __builtin_amdgcn_s_setprio(0);

            __builtin_amdgcn_s_barrier();
            cur ^= 1;
        }

        // ---- epilogue for this half ----
        const float inv = 1.0f / l_r;
        u16* orow = attn_bf + (size_t)(b * SEQ + qg) * 2048 + h * V_HEAD;
#pragma unroll
        for (int ft = 0; ft < 8; ++ft) {
            union { u16 u[4]; uint2 v; } ok;
#pragma unroll
            for (int j = 0; j < 4; ++j) ok.u[j] = f2bf(oacc[ft][j] * inv);
            *(uint2*)(orow + 16 * ft + 4 * lg) = ok.v;
        }
    }
}

// ------------------------------------------------------------------
extern "C" void kernel_launch(void* const* d_in, const int* in_sizes, int n_in,
                              void* d_out, int out_size, void* d_ws, size_t ws_size,
                              hipStream_t stream) {
    const float* x         = (const float*)d_in[0];
    const float* w_query   = (const float*)d_in[1];
    const float* wkv_a     = (const float*)d_in[2];
    const float* wkv_b     = (const float*)d_in[3];
    const float* kv_norm_w = (const float*)d_in[4];
    const float* out_proj  = (const float*)d_in[5];

    u16* x_bf     = (u16*)d_ws;                       // 8M u16 (aliased by attn_bf)
    u16* q_bf     = x_bf + (size_t)8388608;           // 8M
    u16* c_norm   = q_bf + (size_t)8388608;           // 2M
    u16* kvdec_bf = c_norm + (size_t)2097152;         // (unused)
    u16* K_all    = kvdec_bf + (size_t)12582912;      // 8.39M
    u16* Vt       = K_all + (size_t)8388608;          // 8.39M
    u16* wT       = Vt + (size_t)8388608;             // wqT(4M) + wkvaT(1.31M) contiguous
    u16* wkvaT    = wT + (size_t)4194304;
    u16* wkvbT    = wkvaT + (size_t)1310720;          // 1.57M
    u16* opT      = wkvbT + (size_t)1572864;          // 4M
    float* kv     = (float*)(opT + (size_t)4194304);  // 2.62M floats
    float* tab    = kv + (size_t)2621440;             // 131072 floats
    u16* attn_bf  = x_bf;                             // alias (x_bf dead after merged GEMM)
    float* out = (float*)d_out;

    // 128^-0.5 * log2(e): QK scale + exp->exp2 conversion folded into q
    const float qscale2 = 0.08838834764831845f * 1.4426950408889634f;

    prep<<<19456, 256, 0, stream>>>(x, x_bf, w_query, wT, wkv_a, wkvaT,
                                    wkv_b, wkvbT, out_proj, opT, tab);

    // merged q + kv GEMM: N = 2688 = 21 col tiles, fused RoPE(q) epilogue
    gemm128<0><<<672, 256, 0, stream>>>(x_bf, wT, q_bf, kv, tab,
                                        21, 2688, 2048, qscale2);
    rmsnorm_bf<<<NTOK, 256, 0, stream>>>(kv, kv_norm_w, c_norm, tab, K_all);
    // wkv_b GEMM with fused K_all/Vt scatter epilogue: 24 x 32 tiles
    gemm128<2><<<768, 256, 0, stream>>>(c_norm, wkvbT, K_all, Vt, nullptr,
                                        24, 3072, 512, 1.0f);

    attn_mfma<<<512, 256, 0, stream>>>(q_bf, K_all, Vt, attn_bf);

    // out-proj: 16 x 32 tiles
    gemm128<1><<<512, 256, 0, stream>>>(attn_bf, opT, out, nullptr, nullptr,
                                        16, 2048, 2048, 1.0f);
}

// Round 17
// 214.399 us; speedup vs baseline: 1.1804x; 1.0417x over previous
//
#include <hip/hip_runtime.h>
#include <hip/hip_bf16.h>
#include <math.h>

#define BATCH   2
#define SEQ     2048
#define D_IN    2048
#define NHEAD   16
#define QK_ROPE 64
#define QK_NOPE 64
#define QK_HEAD 128
#define V_HEAD  128
#define KV_RANK 512
#define KV_W    640          // kv row stride (576 padded to 640)
#define NTOK    (BATCH*SEQ)  // 4096
#define EPS_F   1e-6f

typedef unsigned short u16;
typedef short bf16x8 __attribute__((ext_vector_type(8)));
typedef float f32x4  __attribute__((ext_vector_type(4)));

// native conversion: compiler fuses pairs into v_cvt_pk_bf16_f32 (m240)
__device__ __forceinline__ u16 f2bf(float f) {
    union { __hip_bfloat16 h; u16 u; } c;
    c.h = __float2bfloat16(f);
    return c.u;
}
__device__ __forceinline__ float bf2f(u16 u) {
    return __uint_as_float(((unsigned)u) << 16);
}
__device__ __forceinline__ float exp2_hw(float x) {
    float r;
    asm volatile("v_exp_f32 %0, %1\n\ts_nop 0" : "=v"(r) : "v"(x));
    return r;
}
__device__ __forceinline__ void gload16(const void* g, void* l) {
    __builtin_amdgcn_global_load_lds((const __attribute__((address_space(1))) unsigned int*)g,
                                     (__attribute__((address_space(3))) unsigned int*)l, 16, 0, 0);
}

// ---------------- fused preamble: convert + 4 transposes + rope table -------
__device__ __forceinline__ void transpose_sec(const float* __restrict__ src,
                                              u16* __restrict__ dst,
                                              int N, int K, int bx, int by,
                                              float (*tile)[33], int tid) {
    const int tx = tid & 31, ty = tid >> 5;
    const int nb = bx * 32, kb = by * 32;
#pragma unroll
    for (int i = 0; i < 4; ++i) {
        int k = kb + ty + 8 * i, n = nb + tx;
        tile[ty + 8 * i][tx] = (n < N) ? src[(size_t)k * N + n] : 0.f;
    }
    __syncthreads();
#pragma unroll
    for (int i = 0; i < 4; ++i) {
        int n = nb + ty + 8 * i, k = kb + tx;
        dst[(size_t)n * K + k] = f2bf(tile[tx][ty + 8 * i]);
    }
}

__global__ __launch_bounds__(256) void prep(const float* __restrict__ x, u16* __restrict__ x_bf,
                                            const float* __restrict__ wq, u16* __restrict__ wqT,
                                            const float* __restrict__ wkva, u16* __restrict__ wkvaT,
                                            const float* __restrict__ wkvb, u16* __restrict__ wkvbT,
                                            const float* __restrict__ op, u16* __restrict__ opT,
                                            float* __restrict__ tab) {
    __shared__ float tile[32][33];
    const int idx = blockIdx.x;
    const int tid = threadIdx.x;
    if (idx < 8192) {                      // x fp32 -> bf16, 4/thread
        int gid = idx * 256 + tid;
        float4 v = ((const float4*)x)[gid];
        unsigned lo = (unsigned)f2bf(v.x) | ((unsigned)f2bf(v.y) << 16);
        unsigned hi = (unsigned)f2bf(v.z) | ((unsigned)f2bf(v.w) << 16);
        ((uint2*)x_bf)[gid] = make_uint2(lo, hi);
    } else if (idx < 12288) {              // w_query^T
        int s = idx - 8192;
        transpose_sec(wq, wqT, 2048, 2048, s % 64, s / 64, tile, tid);
    } else if (idx < 13568) {              // wkv_a^T (576 -> pad 640)
        int s = idx - 12288;
        transpose_sec(wkva, wkvaT, 576, 2048, s % 20, s / 20, tile, tid);
    } else if (idx < 15104) {              // wkv_b^T
        int s = idx - 13568;
        transpose_sec(wkvb, wkvbT, 3072, 512, s % 96, s / 96, tile, tid);
    } else if (idx < 19200) {              // out_proj^T
        int s = idx - 15104;
        transpose_sec(op, opT, 2048, 2048, s % 64, s / 64, tile, tid);
    } else {                               // rope cos/sin table
        int gid = (idx - 19200) * 256 + tid;  // < SEQ*32
        int i = gid & 31, s = gid >> 5;
        float freq = __expf(-(float)(2 * i) / 64.0f * 9.210340371976184f);
        float ang = (float)s * freq;
        tab[2 * gid]     = cosf(ang);
        tab[2 * gid + 1] = sinf(ang);
    }
}

// ============ 128x128 bf16 GEMM, BK=32, 2-buf, high occupancy ===============
// (structure measured best at R16: counted-vmcnt(0)-1-deep, 32KB LDS)
template <int EPI>
__global__ __launch_bounds__(256, 4) void gemm128(const u16* __restrict__ A,
                                                  const u16* __restrict__ BT,
                                                  void* __restrict__ out0,
                                                  void* __restrict__ out1,
                                                  const float* __restrict__ tab,
                                                  int gx, int N, int K, float oscale) {
    __shared__ u16 lds[16384];  // 32KB: A 2x8KB @0, B 2x8KB @8192 (u16 idx)
    const int tid = threadIdx.x;
    const int w = tid >> 6, l = tid & 63;
    const int lr = l & 15, lg = l >> 4;
    const int wr = w >> 1, wc = w & 1;
    const int nwg = gridDim.x, q8 = nwg >> 3;
    const int wg = (blockIdx.x & 7) * q8 + (blockIdx.x >> 3);
    const int row0 = (wg / gx) * 128, col0 = (wg % gx) * 128;
    const int NT = K >> 5;

    f32x4 acc[4][4];
#pragma unroll
    for (int m = 0; m < 4; ++m)
#pragma unroll
        for (int n = 0; n < 4; ++n) acc[m][n] = (f32x4){0.f, 0.f, 0.f, 0.f};

    auto stageA = [&](int bufi, int kt) {
        u16* base = lds + bufi * 4096;
        const u16* g = A + (size_t)row0 * K + kt * 32;
#pragma unroll
        for (int i = 0; i < 2; ++i) {
            int L = (i * 256 + tid) * 16;                 // linear LDS byte
            int R = L >> 7;
            int c = ((((L >> 4) & 7) ^ (R & 7)) << 4);    // unswizzled byte col
            gload16(g + (size_t)(2 * R + (c >> 6)) * K + ((c & 63) >> 1), base + (L >> 1));
        }
    };
    auto stageB = [&](int bufi, int kt) {
        u16* base = lds + 8192 + bufi * 4096;
        const u16* g = BT + (size_t)col0 * K + kt * 32;
#pragma unroll
        for (int i = 0; i < 2; ++i) {
            int L = (i * 256 + tid) * 16;
            int R = L >> 7;
            int c = ((((L >> 4) & 7) ^ (R & 7)) << 4);
            gload16(g + (size_t)(2 * R + (c >> 6)) * K + ((c & 63) >> 1), base + (L >> 1));
        }
    };

    stageA(0, 0); stageB(0, 0);

    for (int t = 0; t < NT; ++t) {
        const int buf = t & 1;
        u16* Ab = lds + buf * 4096;
        u16* Bb = lds + 8192 + buf * 4096;
        asm volatile("s_waitcnt vmcnt(0)" ::: "memory");
        __builtin_amdgcn_s_barrier();
        asm volatile("" ::: "memory");

        bf16x8 af[4], bfg[4];
#pragma unroll
        for (int n = 0; n < 4; ++n) {
            int grow = wc * 64 + n * 16 + lr;
            int R = grow >> 1;
            int c = ((grow & 1) << 6) + (lg << 4);
            bfg[n] = *(const bf16x8*)&Bb[(R * 128 + (c ^ ((R & 7) << 4))) >> 1];
        }
#pragma unroll
        for (int i = 0; i < 4; ++i) {
            int grow = wr * 64 + i * 16 + lr;
            int R = grow >> 1;
            int c = ((grow & 1) << 6) + (lg << 4);
            af[i] = *(const bf16x8*)&Ab[(R * 128 + (c ^ ((R & 7) << 4))) >> 1];
        }
        if (t + 1 < NT) { stageA(buf ^ 1, t + 1); stageB(buf ^ 1, t + 1); }
#pragma unroll
        for (int i = 0; i < 4; ++i)
#pragma unroll
            for (int n = 0; n < 4; ++n)
                acc[i][n] = __builtin_amdgcn_mfma_f32_16x16x32_bf16(af[i], bfg[n], acc[i][n], 0, 0, 0);
    }

    if (EPI == 0) {
        u16* qp = (u16*)out0;
        float* kvp = (float*)out1;
        const bool pe = (wc == 1);
#pragma unroll
        for (int m = 0; m < 4; ++m)
#pragma unroll
            for (int n = 0; n < 4; ++n) {
                int c = col0 + wc * 64 + n * 16 + lr;
#pragma unroll
                for (int j = 0; j < 4; ++j) {
                    int r = row0 + wr * 64 + m * 16 + 4 * lg + j;
                    float v = acc[m][n][j];
                    if (c < 2048) {
                        v *= oscale;
                        if (pe) {
                            int s = r & (SEQ - 1);
                            int ip = (16 * n + lr) >> 1;
                            float2 cs = ((const float2*)tab)[s * 32 + ip];
                            float part = __shfl_xor(v, 1);
                            v = (lr & 1) ? (v * cs.x + part * cs.y)
                                         : (v * cs.x - part * cs.y);
                        }
                        qp[(size_t)r * 2048 + c] = f2bf(v);
                    } else {
                        kvp[(size_t)r * KV_W + (c - 2048)] = v;
                    }
                }
            }
    } else if (EPI == 1) {
        float* C = (float*)out0;
#pragma unroll
        for (int m = 0; m < 4; ++m)
#pragma unroll
            for (int n = 0; n < 4; ++n) {
                int c = col0 + wc * 64 + n * 16 + lr;
#pragma unroll
                for (int j = 0; j < 4; ++j) {
                    int r = row0 + wr * 64 + m * 16 + 4 * lg + j;
                    C[(size_t)r * N + c] = acc[m][n][j];
                }
            }
    } else {  // EPI == 2: K_all / Vt scatter
        u16* Kall = (u16*)out0;
        u16* Vt   = (u16*)out1;
#pragma unroll
        for (int m = 0; m < 4; ++m) {
            int r0 = row0 + wr * 64 + m * 16 + 4 * lg;
            int b  = r0 >> 11;
            int s0 = r0 & (SEQ - 1);
#pragma unroll
            for (int n = 0; n < 4; ++n) {
                int c = col0 + wc * 64 + n * 16 + lr;
                int h = (unsigned)c / 192u;
                int cr = c - h * 192;
                int bh = b * NHEAD + h;
                if (cr < 64) {
#pragma unroll
                    for (int j = 0; j < 4; ++j) {
                        int s = s0 + j;
                        Kall[((size_t)bh * SEQ + s) * 128 + (cr ^ ((s & 7) << 3))] = f2bf(acc[m][n][j]);
                    }
                } else {
                    int d = cr - 64;
                    union { u16 u[4]; uint2 v; } pk;
#pragma unroll
                    for (int j = 0; j < 4; ++j) pk.u[j] = f2bf(acc[m][n][j]);
                    size_t base = ((size_t)bh * 128 + d) * SEQ + (s0 & ~63);
                    *(uint2*)&Vt[base + ((s0 & 63) ^ ((d & 7) << 3))] = pk.v;
                }
            }
        }
    }
}

// -------- RMS norm + fused k_pe build: one block per (b,s) row --------------
__global__ __launch_bounds__(256) void rmsnorm_bf(const float* __restrict__ kv,
                                                  const float* __restrict__ w,
                                                  u16* __restrict__ c_norm,
                                                  const float* __restrict__ tab,
                                                  u16* __restrict__ K_all) {
    __shared__ float red[256];
    const int row = blockIdx.x, t = threadIdx.x;
    const float* src = kv + (size_t)row * KV_W;
    float v0 = src[t], v1 = src[t + 256];
    red[t] = v0 * v0 + v1 * v1;
    __syncthreads();
    for (int s = 128; s > 0; s >>= 1) {
        if (t < s) red[t] += red[t + s];
        __syncthreads();
    }
    const float inv = rsqrtf(red[0] / (float)KV_RANK + EPS_F);
    u16* dst = c_norm + (size_t)row * KV_RANK;
    dst[t]       = f2bf(v0 * inv * w[t]);
    dst[t + 256] = f2bf(v1 * inv * w[t + 256]);

    if (t < 16) {  // fused k_pe: rope kv[512..575] -> 16 head slices
        const int dq = t;
        const int s = row & (SEQ - 1);
        const int b = row >> 11;
        float4 v = *(const float4*)(src + KV_RANK + 4 * dq);
        const int i0 = 2 * dq;
        float2 cs0 = ((const float2*)tab)[s * 32 + i0];
        float2 cs1 = ((const float2*)tab)[s * 32 + i0 + 1];
        union { u16 u[4]; uint2 w2; } pk;
        pk.u[0] = f2bf(v.x * cs0.x - v.y * cs0.y);
        pk.u[1] = f2bf(v.y * cs0.x + v.x * cs0.y);
        pk.u[2] = f2bf(v.z * cs1.x - v.w * cs1.y);
        pk.u[3] = f2bf(v.w * cs1.x + v.z * cs1.y);
        const int idx = (64 + 4 * dq) ^ ((s & 7) << 3);
#pragma unroll
        for (int h = 0; h < NHEAD; ++h) {
            int bh = b * NHEAD + h;
            *(uint2*)&K_all[((size_t)bh * SEQ + s) * 128 + idx] = pk.w2;
        }
    }
}

// ---------------- flash attention: pair-balanced blocks ---------------------
// VALU diet vs R16: native cvt (pk-fused), per-lane l_r (epilogue-only sum
// reduce), P-write issued before rescale so ds_write drains under VALU.
#define QTILE 64
#define KTILE 64

__global__ __launch_bounds__(256, 2) void attn_mfma(const u16* __restrict__ q_bf,
                                                    const u16* __restrict__ K_all,
                                                    const u16* __restrict__ Vt,
                                                    u16* __restrict__ attn_bf) {
    __shared__ u16 Kbuf[2][KTILE * 128];   // 2 x 16KB
    __shared__ u16 Vbuf[2][128 * KTILE];   // 2 x 16KB
    __shared__ u16 Plds[4][16 * KTILE];    // 8KB, wave-private

    const int idx = blockIdx.x;                       // 0..511
    const int bh = (idx & 7) + 8 * (idx >> 7);        // 4 heads per XCD (4MB = L2)
    const int pi = (idx >> 3) & 15;                   // pair index
    const int b = bh >> 4, h = bh & 15;

    const int tid = threadIdx.x;
    const int w = tid >> 6, l = tid & 63;
    const int lr = l & 15, lg = l >> 4;
    const u16* Kb = K_all + (size_t)bh * SEQ * 128;
    const u16* Vb = Vt + (size_t)bh * 128 * SEQ;
    const int sw = (lr & 7) << 3;                     // u16-index XOR
    u16* pw = Plds[w];

    auto stage = [&](int bufi, int k0) {
        u16* kb = Kbuf[bufi];
        u16* vb = Vbuf[bufi];
#pragma unroll
        for (int it = 0; it < 4; ++it) {              // K: 1024 x 16B chunks
            int ci = it * 256 + tid;
            gload16(Kb + (((size_t)(k0 + (ci >> 4))) << 7) + ((ci & 15) << 3),
                    kb + (ci << 3));
        }
#pragma unroll
        for (int it = 0; it < 4; ++it) {              // V: 1024 x 16B chunks
            int ci = it * 256 + tid;
            gload16(Vb + (size_t)(ci >> 3) * SEQ + k0 + ((ci & 7) << 3),
                    vb + (ci << 3));
        }
    };

    const int qbA = (31 - pi) * QTILE;
    const int qbB = pi * QTILE;

    stage(0, 0);
    int cur = 0;
    for (int half = 0; half < 2; ++half) {
        const int qbase = half ? qbB : qbA;
        const int nkt = (qbase >> 6) + 1;
        const int qg = qbase + 16 * w + lr;

        const u16* qrow = q_bf + (size_t)(b * SEQ + qg) * 2048 + h * QK_HEAD;
        bf16x8 qf[4];
#pragma unroll
        for (int dc = 0; dc < 4; ++dc) qf[dc] = *(const bf16x8*)(qrow + dc * 32 + lg * 8);

        f32x4 oacc[8];
#pragma unroll
        for (int ft = 0; ft < 8; ++ft) oacc[ft] = (f32x4){0.f, 0.f, 0.f, 0.f};
        float m_r = -1e30f, l_r = 0.f;   // l_r is PER-LANE (reduced at epilogue)

        for (int kt = 0; kt < nkt; ++kt) {
            const int k0 = kt * KTILE;
            if (kt + 1 < nkt) {
                stage(cur ^ 1, k0 + KTILE);
                asm volatile("s_waitcnt vmcnt(8)" ::: "memory");
            } else if (half == 0) {
                stage(cur ^ 1, 0);                    // prefetch half-B tile 0
                asm volatile("s_waitcnt vmcnt(8)" ::: "memory");
            } else {
                asm volatile("s_waitcnt vmcnt(0)" ::: "memory");
            }
            __builtin_amdgcn_s_barrier();
            __builtin_amdgcn_sched_barrier(0);

            const u16* kb = Kbuf[cur];
            const u16* vb = Vbuf[cur];

            // ---- S^T = K @ Q^T ----
            f32x4 s[4];
            __builtin_amdgcn_s_setprio(1);
#pragma unroll
            for (int f = 0; f < 4; ++f) {
                s[f] = (f32x4){0.f, 0.f, 0.f, 0.f};
#pragma unroll
                for (int dc = 0; dc < 4; ++dc) {
                    bf16x8 kf = *(const bf16x8*)&kb[(16 * f + lr) * 128 + ((32 * dc + 8 * lg) ^ sw)];
                    s[f] = __builtin_amdgcn_mfma_f32_16x16x32_bf16(kf, qf[dc], s[f], 0, 0, 0);
                }
            }
            __builtin_amdgcn_s_setprio(0);

            // ---- causal mask (diagonal tile only) ----
            if (kt == nkt - 1) {
#pragma unroll
                for (int f = 0; f < 4; ++f)
#pragma unroll
                    for (int j = 0; j < 4; ++j)
                        if (k0 + 16 * f + 4 * lg + j > qg) s[f][j] = -1e30f;
            }

            // ---- online softmax: row-max (2 shfl), exp2, immediate P-write --
            float t0 = fmaxf(fmaxf(s[0][0], s[0][1]), fmaxf(s[0][2], s[0][3]));
            float t1 = fmaxf(fmaxf(s[1][0], s[1][1]), fmaxf(s[1][2], s[1][3]));
            float t2 = fmaxf(fmaxf(s[2][0], s[2][1]), fmaxf(s[2][2], s[2][3]));
            float t3 = fmaxf(fmaxf(s[3][0], s[3][1]), fmaxf(s[3][2], s[3][3]));
            float t = fmaxf(fmaxf(t0, t1), fmaxf(t2, t3));
            t = fmaxf(t, __shfl_xor(t, 16));
            t = fmaxf(t, __shfl_xor(t, 32));
            bool up = (t > m_r + 11.5f);              // 2^11.5 headroom
            float newm = up ? t : m_r;
            float sf_ = up ? exp2_hw(m_r - t) : 1.0f;
            m_r = newm;
#pragma unroll
            for (int f = 0; f < 4; ++f)
#pragma unroll
                for (int j = 0; j < 4; ++j) s[f][j] = exp2_hw(s[f][j] - newm);

            // P -> wave-private LDS first (writes drain under following VALU)
#pragma unroll
            for (int f = 0; f < 4; ++f) {
                union { u16 u[4]; uint2 v; } pk;
#pragma unroll
                for (int j = 0; j < 4; ++j) pk.u[j] = f2bf(s[f][j]);
                *(uint2*)&pw[lr * 64 + ((16 * f + 4 * lg) ^ sw)] = pk.v;
            }

            // per-lane row-sum + rescale while ds_writes are in flight
            float rs = 0.f;
#pragma unroll
            for (int f = 0; f < 4; ++f)
#pragma unroll
                for (int j = 0; j < 4; ++j) rs += s[f][j];
            l_r = l_r * sf_ + rs;
            if (__any(up)) {
#pragma unroll
                for (int ft = 0; ft < 8; ++ft)
#pragma unroll
                    for (int j = 0; j < 4; ++j) oacc[ft][j] *= sf_;
            }

            asm volatile("s_waitcnt lgkmcnt(0)" ::: "memory");
            bf16x8 pfr[2];
#pragma unroll
            for (int ks = 0; ks < 2; ++ks)
                pfr[ks] = *(const bf16x8*)&pw[lr * 64 + ((32 * ks + 8 * lg) ^ sw)];

            // ---- O^T += V^T @ P^T ----
            __builtin_amdgcn_s_setprio(1);
#pragma unroll
            for (int ft = 0; ft < 8; ++ft) {
                int d = 16 * ft + lr;
#pragma unroll
                for (int ks = 0; ks < 2; ++ks) {
                    bf16x8 vf = *(const bf16x8*)&vb[d * 64 + ((32 * ks + 8 * lg) ^ sw)];
                    oacc[ft] = __builtin_amdgcn_mfma_f32_16x16x32_bf16(vf, pfr[ks], oacc[ft], 0, 0, 0);
                }
            }
            __builtin_amdgcn_s_setprio(0);

            __builtin_amdgcn_s_barrier();
            cur ^= 1;
        }

        // ---- epilogue: reduce per-lane l_r across the row's 4 lanes --------
        float lsum = l_r + __shfl_xor(l_r, 16);
        lsum += __shfl_xor(lsum, 32);
        const float inv = 1.0f / lsum;
        u16* orow = attn_bf + (size_t)(b * SEQ + qg) * 2048 + h * V_HEAD;
#pragma unroll
        for (int ft = 0; ft < 8; ++ft) {
            union { u16 u[4]; uint2 v; } ok;
#pragma unroll
            for (int j = 0; j < 4; ++j) ok.u[j] = f2bf(oacc[ft][j] * inv);
            *(uint2*)(orow + 16 * ft + 4 * lg) = ok.v;
        }
    }
}

// ------------------------------------------------------------------
extern "C" void kernel_launch(void* const* d_in, const int* in_sizes, int n_in,
                              void* d_out, int out_size, void* d_ws, size_t ws_size,
                              hipStream_t stream) {
    const float* x         = (const float*)d_in[0];
    const float* w_query   = (const float*)d_in[1];
    const float* wkv_a     = (const float*)d_in[2];
    const float* wkv_b     = (const float*)d_in[3];
    const float* kv_norm_w = (const float*)d_in[4];
    const float* out_proj  = (const float*)d_in[5];

    u16* x_bf     = (u16*)d_ws;                       // 8M u16 (aliased by attn_bf)
    u16* q_bf     = x_bf + (size_t)8388608;           // 8M
    u16* c_norm   = q_bf + (size_t)8388608;           // 2M
    u16* kvdec_bf = c_norm + (size_t)2097152;         // (unused)
    u16* K_all    = kvdec_bf + (size_t)12582912;      // 8.39M
    u16* Vt       = K_all + (size_t)8388608;          // 8.39M
    u16* wT       = Vt + (size_t)8388608;             // wqT(4M) + wkvaT(1.31M) contiguous
    u16* wkvaT    = wT + (size_t)4194304;
    u16* wkvbT    = wkvaT + (size_t)1310720;          // 1.57M
    u16* opT      = wkvbT + (size_t)1572864;          // 4M
    float* kv     = (float*)(opT + (size_t)4194304);  // 2.62M floats
    float* tab    = kv + (size_t)2621440;             // 131072 floats
    u16* attn_bf  = x_bf;                             // alias (x_bf dead after merged GEMM)
    float* out = (float*)d_out;

    // 128^-0.5 * log2(e): QK scale + exp->exp2 conversion folded into q
    const float qscale2 = 0.08838834764831845f * 1.4426950408889634f;

    prep<<<19456, 256, 0, stream>>>(x, x_bf, w_query, wT, wkv_a, wkvaT,
                                    wkv_b, wkvbT, out_proj, opT, tab);

    // merged q + kv GEMM: N = 2688 = 21 col tiles, fused RoPE(q) epilogue
    gemm128<0><<<672, 256, 0, stream>>>(x_bf, wT, q_bf, kv, tab,
                                        21, 2688, 2048, qscale2);
    rmsnorm_bf<<<NTOK, 256, 0, stream>>>(kv, kv_norm_w, c_norm, tab, K_all);
    // wkv_b GEMM with fused K_all/Vt scatter epilogue: 24 x 32 tiles
    gemm128<2><<<768, 256, 0, stream>>>(c_norm, wkvbT, K_all, Vt, nullptr,
                                        24, 3072, 512, 1.0f);

    attn_mfma<<<512, 256, 0, stream>>>(q_bf, K_all, Vt, attn_bf);

    // out-proj: 16 x 32 tiles
    gemm128<1><<<512, 256, 0, stream>>>(attn_bf, opT, out, nullptr, nullptr,
                                        16, 2048, 2048, 1.0f);
}